// Round 1
// baseline (1401.059 us; speedup 1.0000x reference)
//
#include <hip/hip_runtime.h>
#include <math.h>

#define HID 128
#define NF  128
#define NG  50

__device__ inline float ssp(float x) {
    // softplus(x) - log(2), numerically stable
    float ax = fabsf(x);
    float sp = fmaxf(x, 0.0f) + log1pf(expf(-ax));
    return sp - 0.69314718055994531f;
}

// ---------------- weight pre-transpose ----------------
// 4 matrices 128x128 ([o][k] -> [k][o]) + mlp_w0 128x50 -> [50][128]
__global__ void transpose_weights(const float* __restrict__ lin1_w,
                                  const float* __restrict__ lin2_w,
                                  const float* __restrict__ lin_w,
                                  const float* __restrict__ mlp_w2,
                                  const float* __restrict__ mlp_w0,
                                  float* __restrict__ wt1,
                                  float* __restrict__ wt2,
                                  float* __restrict__ wtf,
                                  float* __restrict__ w2t,
                                  float* __restrict__ w0t) {
    int idx = blockIdx.x * 256 + threadIdx.x;
    if (idx < 65536) {
        int m = idx >> 14, i = idx & 16383;
        int r = i >> 7, c = i & 127;
        const float* s = (m == 0) ? lin1_w : (m == 1) ? lin2_w : (m == 2) ? lin_w : mlp_w2;
        float*       d = (m == 0) ? wt1    : (m == 1) ? wt2    : (m == 2) ? wtf   : w2t;
        d[c * 128 + r] = s[i];
    } else if (idx < 65536 + 6400) {
        int i = idx - 65536;
        int r = i / 50, c = i - r * 50;
        w0t[c * 128 + r] = mlp_w0[i];
    }
}

// ---------------- node GEMM: out = (A [+A2]) (pre-act?) @ W^T (+bias) --------
// WT is pre-transposed [k][o]. 32-row tile per block, 256 threads, 4x4/thread.
template<bool ADD2, bool PREACT, bool BIAS, bool ZERO>
__global__ __launch_bounds__(256) void node_gemm(
    const float* A, const float* A2,
    const float* __restrict__ WT, const float* __restrict__ bias,
    float* out, float* zbuf, int n_rows)
{
    __shared__ float wt[128 * 128];
    __shared__ float at[32 * 128];
    const int tid = threadIdx.x;
    const int n0 = blockIdx.x * 32;

    #pragma unroll
    for (int t = 0; t < 16; ++t) {
        int f = tid + t * 256;
        *(float4*)&wt[f * 4] = ((const float4*)WT)[f];
    }
    #pragma unroll
    for (int t = 0; t < 4; ++t) {
        int f = tid + t * 256;          // 1024 float4 = 32 rows x 128
        int row = f >> 5, c4 = f & 31;
        float4 v = make_float4(0.f, 0.f, 0.f, 0.f);
        if (n0 + row < n_rows) {
            v = ((const float4*)A)[(size_t)(n0 + row) * 32 + c4];
            if (ADD2) {
                float4 w = ((const float4*)A2)[(size_t)(n0 + row) * 32 + c4];
                v.x += w.x; v.y += w.y; v.z += w.z; v.w += w.w;
            }
            if (PREACT) { v.x = ssp(v.x); v.y = ssp(v.y); v.z = ssp(v.z); v.w = ssp(v.w); }
        }
        *(float4*)&at[row * 128 + c4 * 4] = v;
    }
    __syncthreads();

    const int c = tid & 31, rg = tid >> 5;
    const int o0 = c * 4, r0 = rg * 4;
    float acc[4][4];
    #pragma unroll
    for (int i = 0; i < 4; ++i)
        #pragma unroll
        for (int j = 0; j < 4; ++j) acc[i][j] = 0.f;

    #pragma unroll 4
    for (int k = 0; k < 128; ++k) {
        float4 wv = *(const float4*)&wt[k * 128 + o0];
        #pragma unroll
        for (int i = 0; i < 4; ++i) {
            float a = at[(r0 + i) * 128 + k];
            acc[i][0] += a * wv.x; acc[i][1] += a * wv.y;
            acc[i][2] += a * wv.z; acc[i][3] += a * wv.w;
        }
    }

    float4 bv = make_float4(0.f, 0.f, 0.f, 0.f);
    if (BIAS) bv = ((const float4*)bias)[c];
    #pragma unroll
    for (int i = 0; i < 4; ++i) {
        int n = n0 + r0 + i;
        if (n < n_rows) {
            float4 v = make_float4(acc[i][0] + bv.x, acc[i][1] + bv.y,
                                   acc[i][2] + bv.z, acc[i][3] + bv.w);
            ((float4*)out)[(size_t)n * 32 + c] = v;
            if (ZERO) {
                ((float4*)zbuf)[(size_t)n * 32 + c] = make_float4(0.f, 0.f, 0.f, 0.f);
            }
        }
    }
}

// ---------------- edge kernel: per-edge MLP + gather + atomic scatter --------
// 512 threads, 128 edges/block. thread: c = tid&31 -> o0 = 4c ; jg = tid>>5 ->
// j0 = 8*jg (8 edges). LDS: w0t 25.6K + w2t 64K + buf 64K (ea then u) ~155K.
__global__ __launch_bounds__(512) void edge_kernel(
    const int* __restrict__ srcI, const int* __restrict__ dstI,
    const float* __restrict__ ew, const float* __restrict__ ea,
    const float* __restrict__ w0t, const float* __restrict__ b0,
    const float* __restrict__ w2t, const float* __restrict__ b2,
    const float* __restrict__ h1, float* agg, int n_edges)
{
    __shared__ float w0s[50 * 128];
    __shared__ float w2s[128 * 128];
    __shared__ float buf[128 * 128];    // eas[128][52] then us[128][128]
    __shared__ float cws[128];
    __shared__ int   srcs[128], dsts[128];

    const int tid = threadIdx.x;
    const int e0 = blockIdx.x * 128;
    const int nval = min(128, n_edges - e0);

    for (int f = tid; f < 1600; f += 512) ((float4*)w0s)[f] = ((const float4*)w0t)[f];
    for (int f = tid; f < 4096; f += 512) ((float4*)w2s)[f] = ((const float4*)w2t)[f];
    for (int i = tid; i < nval * 50; i += 512) {
        int j = i / 50, k = i - j * 50;
        buf[j * 52 + k] = ea[(size_t)e0 * 50 + i];
    }
    if (tid < 128) {
        float cwv = 0.f; int s = 0, d = 0;
        if (tid < nval) {
            int e = e0 + tid;
            cwv = 0.5f * (cosf(ew[e] * 0.31415926535897931f) + 1.0f);
            s = srcI[e]; d = dstI[e];
        }
        cws[tid] = cwv; srcs[tid] = s; dsts[tid] = d;
    }
    __syncthreads();

    const int c = tid & 31, jg = tid >> 5;
    const int o0 = c * 4, j0 = jg * 8;

    // phase 1: t = ea @ w0^T + b0
    float4 b0v = ((const float4*)b0)[c];
    float t[8][4];
    #pragma unroll
    for (int i = 0; i < 8; ++i) {
        t[i][0] = b0v.x; t[i][1] = b0v.y; t[i][2] = b0v.z; t[i][3] = b0v.w;
    }
    #pragma unroll 2
    for (int k = 0; k < 50; ++k) {
        float4 wv = *(const float4*)&w0s[k * 128 + o0];
        #pragma unroll
        for (int i = 0; i < 8; ++i) {
            float a = buf[(j0 + i) * 52 + k];
            t[i][0] += a * wv.x; t[i][1] += a * wv.y;
            t[i][2] += a * wv.z; t[i][3] += a * wv.w;
        }
    }
    __syncthreads();            // all ea reads done before overwriting buf

    // write u = ssp(t) into buf as [128][128]
    #pragma unroll
    for (int i = 0; i < 8; ++i) {
        float4 u;
        u.x = ssp(t[i][0]); u.y = ssp(t[i][1]);
        u.z = ssp(t[i][2]); u.w = ssp(t[i][3]);
        *(float4*)&buf[(j0 + i) * 128 + o0] = u;
    }
    __syncthreads();

    // phase 2: W = u @ w2^T + b2
    float4 b2v = ((const float4*)b2)[c];
    float w[8][4];
    #pragma unroll
    for (int i = 0; i < 8; ++i) {
        w[i][0] = b2v.x; w[i][1] = b2v.y; w[i][2] = b2v.z; w[i][3] = b2v.w;
    }
    #pragma unroll 2
    for (int k = 0; k < 128; ++k) {
        float4 wv = *(const float4*)&w2s[k * 128 + o0];
        #pragma unroll
        for (int i = 0; i < 8; ++i) {
            float u = buf[(j0 + i) * 128 + k];
            w[i][0] += u * wv.x; w[i][1] += u * wv.y;
            w[i][2] += u * wv.z; w[i][3] += u * wv.w;
        }
    }

    // gather h1[src], scale by c, atomic scatter into agg[dst]
    #pragma unroll
    for (int i = 0; i < 8; ++i) {
        int j = j0 + i;
        if (j < nval) {
            int s = srcs[j], d = dsts[j];
            float cw = cws[j];
            float4 hv = ((const float4*)h1)[(size_t)s * 32 + c];
            float m0 = cw * w[i][0] * hv.x;
            float m1 = cw * w[i][1] * hv.y;
            float m2 = cw * w[i][2] * hv.z;
            float m3 = cw * w[i][3] * hv.w;
            float* ap = &agg[(size_t)d * 128 + o0];
            atomicAdd(ap + 0, m0); atomicAdd(ap + 1, m1);
            atomicAdd(ap + 2, m2); atomicAdd(ap + 3, m3);
        }
    }
}

extern "C" void kernel_launch(void* const* d_in, const int* in_sizes, int n_in,
                              void* d_out, int out_size, void* d_ws, size_t ws_size,
                              hipStream_t stream) {
    const float* h       = (const float*)d_in[0];
    const int*   ei      = (const int*)  d_in[1];
    const float* ew      = (const float*)d_in[2];
    const float* ea      = (const float*)d_in[3];
    const float* mlp_w0  = (const float*)d_in[4];
    const float* mlp_b0  = (const float*)d_in[5];
    const float* mlp_w2  = (const float*)d_in[6];
    const float* mlp_b2  = (const float*)d_in[7];
    const float* lin1_w  = (const float*)d_in[8];
    const float* lin2_w  = (const float*)d_in[9];
    const float* lin2_b  = (const float*)d_in[10];
    const float* lin_w   = (const float*)d_in[11];
    const float* lin_b   = (const float*)d_in[12];
    float* out = (float*)d_out;
    float* ws  = (float*)d_ws;

    const int N = in_sizes[0] / HID;       // 50000
    const int E = in_sizes[2];             // 600000

    float* h1  = ws;                        // N*128
    float* agg = ws + (size_t)N * 128;      // N*128
    float* wt1 = agg + (size_t)N * 128;
    float* wt2 = wt1 + 16384;
    float* wtf = wt2 + 16384;
    float* w2t = wtf + 16384;
    float* w0t = w2t + 16384;

    const int* srcI = ei;
    const int* dstI = ei + E;

    transpose_weights<<<281, 256, 0, stream>>>(lin1_w, lin2_w, lin_w, mlp_w2,
                                               mlp_w0, wt1, wt2, wtf, w2t, w0t);

    int ngrid = (N + 31) / 32;
    // h1 = h @ lin1^T ; agg = 0
    node_gemm<false, false, false, true><<<ngrid, 256, 0, stream>>>(
        h, nullptr, wt1, nullptr, h1, agg, N);

    int egrid = (E + 127) / 128;
    edge_kernel<<<egrid, 512, 0, stream>>>(srcI, dstI, ew, ea, w0t, mlp_b0,
                                           w2t, mlp_b2, h1, agg, E);

    // h2 = (h1 + agg) @ lin2^T + b2   (in-place into h1 buffer; per-block rows)
    node_gemm<true, false, true, false><<<ngrid, 256, 0, stream>>>(
        h1, agg, wt2, lin2_b, h1, nullptr, N);

    // out = ssp(h2) @ lin^T + lin_b
    node_gemm<false, true, true, false><<<ngrid, 256, 0, stream>>>(
        h1, nullptr, wtf, lin_b, out, nullptr, N);
}

// Round 2
// 852.295 us; speedup vs baseline: 1.6439x; 1.6439x over previous
//
#include <hip/hip_runtime.h>
#include <math.h>

#define HID 128
#define NF  128
#define NG  50

typedef unsigned short ushort_t;
typedef unsigned short us8 __attribute__((ext_vector_type(8)));
typedef __bf16 bf16x8 __attribute__((ext_vector_type(8)));
typedef float f32x4 __attribute__((ext_vector_type(4)));

__device__ inline float ssp(float x) {
    float ax = fabsf(x);
    float sp = fmaxf(x, 0.0f) + log1pf(expf(-ax));
    return sp - 0.69314718055994531f;
}

__device__ __host__ inline ushort_t f2bf(float f) {
    unsigned u = __builtin_bit_cast(unsigned, f);
    unsigned r = (u + 0x7fffu + ((u >> 16) & 1u)) >> 16;
    return (ushort_t)r;
}
__device__ inline float bf2f(ushort_t h) {
    unsigned u = ((unsigned)h) << 16;
    return __builtin_bit_cast(float, u);
}

// ---------------- weight prep: f32 transposes + bf16 pre-swizzled ----------
// swizzle: element (row o, col k) stored at k ^ ((o&7)<<3)  (XOR of elem idx,
// == byte ^ ((o&7)<<4) for 2B elems) -> conflict-free ds_read_b128 later.
__global__ void prep_weights(const float* __restrict__ lin1_w,
                             const float* __restrict__ lin2_w,
                             const float* __restrict__ lin_w,
                             const float* __restrict__ mlp_w0,
                             const float* __restrict__ mlp_w2,
                             float* __restrict__ wt1,
                             float* __restrict__ wt2,
                             float* __restrict__ wtf,
                             ushort_t* __restrict__ w0b,
                             ushort_t* __restrict__ w2b) {
    int idx = blockIdx.x * 256 + threadIdx.x;
    if (idx < 49152) {
        int m = idx >> 14, i = idx & 16383;
        int r = i >> 7, c = i & 127;
        const float* s = (m == 0) ? lin1_w : (m == 1) ? lin2_w : lin_w;
        float*       d = (m == 0) ? wt1    : (m == 1) ? wt2    : wtf;
        d[c * 128 + r] = s[i];
    } else if (idx < 49152 + 8192) {
        int i = idx - 49152;            // o*64 + k
        int o = i >> 6, k = i & 63;
        float v = (k < 50) ? mlp_w0[o * 50 + k] : 0.f;
        w0b[o * 64 + (k ^ ((o & 7) << 3))] = f2bf(v);
    } else if (idx < 49152 + 8192 + 16384) {
        int i = idx - 57344;            // o*128 + k
        int o = i >> 7, k = i & 127;
        w2b[o * 128 + (k ^ ((o & 7) << 3))] = f2bf(mlp_w2[i]);
    }
}

// ---------------- CSR build ----------------
__global__ void zero_ints(int* p, int n) {
    int i = blockIdx.x * 256 + threadIdx.x;
    if (i < n) p[i] = 0;
}
__global__ void hist_kernel(const int* __restrict__ dst, int* counts, int E) {
    int e = blockIdx.x * 256 + threadIdx.x;
    if (e < E) atomicAdd(&counts[dst[e]], 1);
}
__global__ __launch_bounds__(1024) void scan_kernel(const int* __restrict__ counts,
                                                    int* __restrict__ off, int n) {
    __shared__ int sums[1024];
    int t = threadIdx.x;
    int chunk = (n + 1023) / 1024;
    int base = t * chunk;
    int s = 0;
    for (int i = 0; i < chunk; ++i) {
        int idx = base + i;
        if (idx < n) s += counts[idx];
    }
    sums[t] = s;
    __syncthreads();
    for (int d = 1; d < 1024; d <<= 1) {
        int v = (t >= d) ? sums[t - d] : 0;
        __syncthreads();
        sums[t] += v;
        __syncthreads();
    }
    int pre = (t == 0) ? 0 : sums[t - 1];
    for (int i = 0; i < chunk; ++i) {
        int idx = base + i;
        if (idx < n) { off[idx] = pre; pre += counts[idx]; }
    }
    if (t == 1023) off[n] = pre;
}
__global__ void scatter_kernel(const int* __restrict__ src, const int* __restrict__ dst,
                               const int* __restrict__ off, int* cursor,
                               int* __restrict__ eperm, int* __restrict__ srcp, int E) {
    int e = blockIdx.x * 256 + threadIdx.x;
    if (e < E) {
        int d = dst[e];
        int slot = atomicAdd(&cursor[d], 1);
        int p = off[d] + slot;
        eperm[p] = e;
        srcp[p] = src[e];
    }
}

// ---------------- node GEMM (f32 VALU, unchanged from R1) ------------------
template<bool ADD2, bool PREACT, bool BIAS>
__global__ __launch_bounds__(256) void node_gemm(
    const float* A, const float* A2,
    const float* __restrict__ WT, const float* __restrict__ bias,
    float* out, int n_rows)
{
    __shared__ float wt[128 * 128];
    __shared__ float at[32 * 128];
    const int tid = threadIdx.x;
    const int n0 = blockIdx.x * 32;

    #pragma unroll
    for (int t = 0; t < 16; ++t) {
        int f = tid + t * 256;
        *(float4*)&wt[f * 4] = ((const float4*)WT)[f];
    }
    #pragma unroll
    for (int t = 0; t < 4; ++t) {
        int f = tid + t * 256;
        int row = f >> 5, c4 = f & 31;
        float4 v = make_float4(0.f, 0.f, 0.f, 0.f);
        if (n0 + row < n_rows) {
            v = ((const float4*)A)[(size_t)(n0 + row) * 32 + c4];
            if (ADD2) {
                float4 w = ((const float4*)A2)[(size_t)(n0 + row) * 32 + c4];
                v.x += w.x; v.y += w.y; v.z += w.z; v.w += w.w;
            }
            if (PREACT) { v.x = ssp(v.x); v.y = ssp(v.y); v.z = ssp(v.z); v.w = ssp(v.w); }
        }
        *(float4*)&at[row * 128 + c4 * 4] = v;
    }
    __syncthreads();

    const int c = tid & 31, rg = tid >> 5;
    const int o0 = c * 4, r0 = rg * 4;
    float acc[4][4];
    #pragma unroll
    for (int i = 0; i < 4; ++i)
        #pragma unroll
        for (int j = 0; j < 4; ++j) acc[i][j] = 0.f;

    #pragma unroll 4
    for (int k = 0; k < 128; ++k) {
        float4 wv = *(const float4*)&wt[k * 128 + o0];
        #pragma unroll
        for (int i = 0; i < 4; ++i) {
            float a = at[(r0 + i) * 128 + k];
            acc[i][0] += a * wv.x; acc[i][1] += a * wv.y;
            acc[i][2] += a * wv.z; acc[i][3] += a * wv.w;
        }
    }

    float4 bv = make_float4(0.f, 0.f, 0.f, 0.f);
    if (BIAS) bv = ((const float4*)bias)[c];
    #pragma unroll
    for (int i = 0; i < 4; ++i) {
        int n = n0 + r0 + i;
        if (n < n_rows) {
            ((float4*)out)[(size_t)n * 32 + c] = make_float4(
                acc[i][0] + bv.x, acc[i][1] + bv.y, acc[i][2] + bv.z, acc[i][3] + bv.w);
        }
    }
}

// ---------------- edge MLP via bf16 MFMA -----------------------------------
// 512 thr = 8 waves; 256 CSR-ordered edges/block. Wave (wr,wc): edges
// wr*128..+127, outs wc*32..+31. msg[pos][out] = c * (ssp(ea@w0^T+b0)@w2^T+b2)
__global__ __launch_bounds__(512, 2) void edge_mfma(
    const int* __restrict__ eperm, const float* __restrict__ ea,
    const float* __restrict__ ew,
    const ushort_t* __restrict__ w0b, const ushort_t* __restrict__ w2b,
    const float* __restrict__ b0g, const float* __restrict__ b2g,
    ushort_t* __restrict__ msg, int pos_base, int pos_end)
{
    __shared__ ushort_t ea_s[256 * 64];    // 32 KB, swizzled rows
    __shared__ ushort_t u_s [256 * 128];   // 64 KB, swizzled rows
    __shared__ ushort_t w0s [128 * 64];    // 16 KB (pre-swizzled in global)
    __shared__ ushort_t w2s [128 * 128];   // 32 KB (pre-swizzled in global)
    __shared__ float    cws [256];

    const int tid = threadIdx.x;
    const int p0 = pos_base + blockIdx.x * 256;

    if (tid < 256) {
        // ea staging: thread handles chunk cc=tid&7 (8 cols) of rows (tid>>3)+32j
        int cc = tid & 7;
        int rb = tid >> 3;
        #pragma unroll
        for (int j = 0; j < 8; ++j) {
            int r = rb + 32 * j;
            int pos = p0 + r;
            us8 v = {0, 0, 0, 0, 0, 0, 0, 0};
            if (pos < pos_end) {
                int e = eperm[pos];
                const float* row = ea + (size_t)e * 50;
                #pragma unroll
                for (int q = 0; q < 8; ++q) {
                    int col = cc * 8 + q;
                    float f = (col < 50) ? row[col] : 0.f;
                    v[q] = f2bf(f);
                }
            }
            *(us8*)&ea_s[r * 64 + ((cc * 8) ^ ((r & 7) << 3))] = v;
        }
    } else {
        int t2 = tid - 256;
        {
            int pos = p0 + t2;
            float cv = 0.f;
            if (pos < pos_end) {
                int e = eperm[pos];
                cv = 0.5f * (cosf(ew[e] * 0.31415926535897931f) + 1.0f);
            }
            cws[t2] = cv;
        }
        #pragma unroll
        for (int i = 0; i < 4; ++i) {
            int q = t2 + 256 * i;
            ((us8*)w0s)[q] = ((const us8*)w0b)[q];
        }
        #pragma unroll
        for (int i = 0; i < 8; ++i) {
            int q = t2 + 256 * i;
            ((us8*)w2s)[q] = ((const us8*)w2b)[q];
        }
    }
    __syncthreads();

    const int lane = tid & 63;
    const int wid  = tid >> 6;
    const int eb = (wid >> 2) * 128;
    const int ob = (wid & 3) * 32;
    const int lm = lane & 15;
    const int lh = lane >> 4;
    const int k8b = lh * 8;

    // ---- GEMM1: t = ea @ w0^T  (K = 64, padded) ----
    f32x4 acc1[8][2];
    #pragma unroll
    for (int mi = 0; mi < 8; ++mi) {
        acc1[mi][0] = (f32x4){0.f, 0.f, 0.f, 0.f};
        acc1[mi][1] = (f32x4){0.f, 0.f, 0.f, 0.f};
    }
    #pragma unroll
    for (int ks = 0; ks < 2; ++ks) {
        int k8 = ks * 32 + k8b;
        bf16x8 bf[2];
        #pragma unroll
        for (int ni = 0; ni < 2; ++ni) {
            int n = ob + ni * 16 + lm;
            bf[ni] = __builtin_bit_cast(bf16x8,
                *(const us8*)&w0s[n * 64 + (k8 ^ ((n & 7) << 3))]);
        }
        #pragma unroll
        for (int mi = 0; mi < 8; ++mi) {
            int m = eb + mi * 16 + lm;
            bf16x8 af = __builtin_bit_cast(bf16x8,
                *(const us8*)&ea_s[m * 64 + (k8 ^ ((m & 7) << 3))]);
            acc1[mi][0] = __builtin_amdgcn_mfma_f32_16x16x32_bf16(af, bf[0], acc1[mi][0], 0, 0, 0);
            acc1[mi][1] = __builtin_amdgcn_mfma_f32_16x16x32_bf16(af, bf[1], acc1[mi][1], 0, 0, 0);
        }
    }

    // u = ssp(t + b0) -> bf16 -> swizzled LDS [edge][out]
    float b0v0 = b0g[ob + lm], b0v1 = b0g[ob + 16 + lm];
    #pragma unroll
    for (int mi = 0; mi < 8; ++mi) {
        int erow = eb + mi * 16 + lh * 4;
        #pragma unroll
        for (int ni = 0; ni < 2; ++ni) {
            int out = ob + ni * 16 + lm;
            float bb = ni ? b0v1 : b0v0;
            #pragma unroll
            for (int r = 0; r < 4; ++r) {
                int edge = erow + r;
                float u = ssp(acc1[mi][ni][r] + bb);
                u_s[edge * 128 + (out ^ ((edge & 7) << 3))] = f2bf(u);
            }
        }
    }
    __syncthreads();

    // ---- GEMM2: W = u @ w2^T  (K = 128) ----
    f32x4 acc2[8][2];
    #pragma unroll
    for (int mi = 0; mi < 8; ++mi) {
        acc2[mi][0] = (f32x4){0.f, 0.f, 0.f, 0.f};
        acc2[mi][1] = (f32x4){0.f, 0.f, 0.f, 0.f};
    }
    #pragma unroll
    for (int ks = 0; ks < 4; ++ks) {
        int k8 = ks * 32 + k8b;
        bf16x8 bf[2];
        #pragma unroll
        for (int ni = 0; ni < 2; ++ni) {
            int n = ob + ni * 16 + lm;
            bf[ni] = __builtin_bit_cast(bf16x8,
                *(const us8*)&w2s[n * 128 + (k8 ^ ((n & 7) << 3))]);
        }
        #pragma unroll
        for (int mi = 0; mi < 8; ++mi) {
            int m = eb + mi * 16 + lm;
            bf16x8 af = __builtin_bit_cast(bf16x8,
                *(const us8*)&u_s[m * 128 + (k8 ^ ((m & 7) << 3))]);
            acc2[mi][0] = __builtin_amdgcn_mfma_f32_16x16x32_bf16(af, bf[0], acc2[mi][0], 0, 0, 0);
            acc2[mi][1] = __builtin_amdgcn_mfma_f32_16x16x32_bf16(af, bf[1], acc2[mi][1], 0, 0, 0);
        }
    }

    // msg[pos][out] = c * (W + b2), bf16
    float b2v0 = b2g[ob + lm], b2v1 = b2g[ob + 16 + lm];
    #pragma unroll
    for (int mi = 0; mi < 8; ++mi) {
        int erow = eb + mi * 16 + lh * 4;
        float cv[4];
        #pragma unroll
        for (int r = 0; r < 4; ++r) cv[r] = cws[erow + r];
        #pragma unroll
        for (int ni = 0; ni < 2; ++ni) {
            int out = ob + ni * 16 + lm;
            float bb = ni ? b2v1 : b2v0;
            #pragma unroll
            for (int r = 0; r < 4; ++r) {
                int pos = p0 + erow + r;
                if (pos < pos_end) {
                    float mval = cv[r] * (acc2[mi][ni][r] + bb);
                    msg[(size_t)(pos - pos_base) * 128 + out] = f2bf(mval);
                }
            }
        }
    }
}

// ---------------- aggregation: one wave per dst node -----------------------
__global__ __launch_bounds__(256) void aggregate(
    const int* __restrict__ off, const int* __restrict__ srcp,
    const ushort_t* __restrict__ msg, const float* __restrict__ h1,
    float* __restrict__ agg, int n_nodes, int clo, int chi, int first)
{
    int wid = threadIdx.x >> 6, lane = threadIdx.x & 63;
    int d = blockIdx.x * 4 + wid;
    if (d >= n_nodes) return;
    int p0 = max(off[d], clo);
    int p1 = min(off[d + 1], chi);
    int ch = lane * 2;
    float ax = 0.f, ay = 0.f;
    if (!first) {
        float2 v = *(const float2*)&agg[(size_t)d * 128 + ch];
        ax = v.x; ay = v.y;
    }
    for (int p = p0; p < p1; ++p) {
        int s = srcp[p];
        unsigned mm = *(const unsigned*)&msg[(size_t)(p - clo) * 128 + ch];
        float2 hv = *(const float2*)&h1[(size_t)s * 128 + ch];
        ax += bf2f((ushort_t)(mm & 0xffffu)) * hv.x;
        ay += bf2f((ushort_t)(mm >> 16)) * hv.y;
    }
    *(float2*)&agg[(size_t)d * 128 + ch] = make_float2(ax, ay);
}

extern "C" void kernel_launch(void* const* d_in, const int* in_sizes, int n_in,
                              void* d_out, int out_size, void* d_ws, size_t ws_size,
                              hipStream_t stream) {
    const float* h       = (const float*)d_in[0];
    const int*   ei      = (const int*)  d_in[1];
    const float* ew      = (const float*)d_in[2];
    const float* ea      = (const float*)d_in[3];
    const float* mlp_w0  = (const float*)d_in[4];
    const float* mlp_b0  = (const float*)d_in[5];
    const float* mlp_w2  = (const float*)d_in[6];
    const float* mlp_b2  = (const float*)d_in[7];
    const float* lin1_w  = (const float*)d_in[8];
    const float* lin2_w  = (const float*)d_in[9];
    const float* lin2_b  = (const float*)d_in[10];
    const float* lin_w   = (const float*)d_in[11];
    const float* lin_b   = (const float*)d_in[12];
    float* out = (float*)d_out;
    float* ws  = (float*)d_ws;

    const int N = in_sizes[0] / HID;       // 50000
    const int E = in_sizes[2];             // 600000
    const int NODE_PAD = ((N + 1) + 175) / 176 * 176;   // ~50001 padded
    const int CH = (E + 1) / 2;                          // 300000 (2 chunks)
    const int CH_ROWS = (CH + 255) & ~255;               // 300032

    // ---- workspace layout (f32 slots) ----
    float* h1   = ws;                                   // N*128
    float* agg  = h1  + (size_t)N * 128;                // N*128
    float* wt1  = agg + (size_t)N * 128;                // 16384
    float* wt2  = wt1 + 16384;
    float* wtf  = wt2 + 16384;
    ushort_t* w0b = (ushort_t*)(wtf + 16384);           // 8192 u16 = 4096 slots
    ushort_t* w2b = (ushort_t*)((float*)w0b + 4096);    // 16384 u16 = 8192 slots
    int* counts = (int*)((float*)w0b + 4096 + 8192);    // NODE_PAD
    int* off    = counts + NODE_PAD;                    // NODE_PAD (needs N+1)
    int* cursor = off + NODE_PAD;                       // NODE_PAD
    int* eperm  = cursor + NODE_PAD;                    // E
    int* srcp   = eperm + E;                            // E
    ushort_t* msg = (ushort_t*)(srcp + E);              // CH_ROWS*128 u16

    const int* srcI = ei;
    const int* dstI = ei + E;

    prep_weights<<<288, 256, 0, stream>>>(lin1_w, lin2_w, lin_w, mlp_w0, mlp_w2,
                                          wt1, wt2, wtf, w0b, w2b);

    // CSR build
    zero_ints<<<(2 * NODE_PAD + 255) / 256, 256, 0, stream>>>(counts, 2 * NODE_PAD); // counts+off... counts,cursor adjacent? zero counts & off region is fine
    zero_ints<<<(NODE_PAD + 255) / 256, 256, 0, stream>>>(cursor, NODE_PAD);
    hist_kernel<<<(E + 255) / 256, 256, 0, stream>>>(dstI, counts, E);
    scan_kernel<<<1, 1024, 0, stream>>>(counts, off, N);
    scatter_kernel<<<(E + 255) / 256, 256, 0, stream>>>(srcI, dstI, off, cursor,
                                                        eperm, srcp, E);

    // h1 = h @ lin1^T
    int ngrid = (N + 31) / 32;
    node_gemm<false, false, false><<<ngrid, 256, 0, stream>>>(h, nullptr, wt1,
                                                              nullptr, h1, N);

    // edge MLP + aggregation, 2 chunks
    int aggrid = (N + 3) / 4;
    for (int c = 0; c < 2; ++c) {
        int clo = c * CH;
        int chi = min(E, clo + CH);
        if (chi <= clo) break;
        int nblk = (chi - clo + 255) / 256;
        edge_mfma<<<nblk, 512, 0, stream>>>(eperm, ea, ew, w0b, w2b,
                                            mlp_b0, mlp_b2, msg, clo, chi);
        aggregate<<<aggrid, 256, 0, stream>>>(off, srcp, msg, h1, agg, N,
                                              clo, chi, c == 0);
    }

    // h2 = (h1 + agg) @ lin2^T + b2   (in-place into h1)
    node_gemm<true, false, true><<<ngrid, 256, 0, stream>>>(h1, agg, wt2,
                                                            lin2_b, h1, N);
    // out = ssp(h2) @ lin^T + lin_b
    node_gemm<false, true, true><<<ngrid, 256, 0, stream>>>(h1, nullptr, wtf,
                                                            lin_b, out, N);
}

// Round 3
// 534.207 us; speedup vs baseline: 2.6227x; 1.5954x over previous
//
#include <hip/hip_runtime.h>
#include <math.h>

#define HID 128
#define NF  128
#define NG  50

typedef unsigned short ushort_t;
typedef unsigned short us8 __attribute__((ext_vector_type(8)));
typedef unsigned short us4 __attribute__((ext_vector_type(4)));
typedef __bf16 bf16x8 __attribute__((ext_vector_type(8)));
typedef float f32x4 __attribute__((ext_vector_type(4)));

__device__ inline float ssp_fast(float x) {
    // softplus(x) - ln2 = max(x,0) + ln2*(log2(1+exp2(-|x|*log2e)) - 1)
    float t = __builtin_amdgcn_exp2f(fabsf(x) * -1.4426950408889634f);
    float l = __builtin_amdgcn_logf(1.0f + t);      // log2
    return fmaxf(x, 0.0f) + 0.6931471805599453f * (l - 1.0f);
}

__device__ __host__ inline ushort_t f2bf(float f) {
    unsigned u = __builtin_bit_cast(unsigned, f);
    unsigned r = (u + 0x7fffu + ((u >> 16) & 1u)) >> 16;
    return (ushort_t)r;
}
__device__ inline float bf2f(ushort_t h) {
    unsigned u = ((unsigned)h) << 16;
    return __builtin_bit_cast(float, u);
}

// ---------------- weight prep: f32 transposes + bf16 pre-swizzled ----------
// swizzle: element (row o, col k) stored at k ^ ((o&7)<<3)
__global__ void prep_weights(const float* __restrict__ lin1_w,
                             const float* __restrict__ lin2_w,
                             const float* __restrict__ lin_w,
                             const float* __restrict__ mlp_w0,
                             const float* __restrict__ mlp_w2,
                             float* __restrict__ wt1,
                             float* __restrict__ wt2,
                             float* __restrict__ wtf,
                             ushort_t* __restrict__ w0b,
                             ushort_t* __restrict__ w2b) {
    int idx = blockIdx.x * 256 + threadIdx.x;
    if (idx < 49152) {
        int m = idx >> 14, i = idx & 16383;
        int r = i >> 7, c = i & 127;
        const float* s = (m == 0) ? lin1_w : (m == 1) ? lin2_w : lin_w;
        float*       d = (m == 0) ? wt1    : (m == 1) ? wt2    : wtf;
        d[c * 128 + r] = s[i];
    } else if (idx < 49152 + 8192) {
        int i = idx - 49152;            // o*64 + k
        int o = i >> 6, k = i & 63;
        float v = (k < 50) ? mlp_w0[o * 50 + k] : 0.f;
        w0b[o * 64 + (k ^ ((o & 7) << 3))] = f2bf(v);
    } else if (idx < 49152 + 8192 + 16384) {
        int i = idx - 57344;            // o*128 + k
        int o = i >> 7, k = i & 127;
        w2b[o * 128 + (k ^ ((o & 7) << 3))] = f2bf(mlp_w2[i]);
    }
}

// ---------------- CSR build ----------------
__global__ void zero_ints(int* p, int n) {
    int i = blockIdx.x * 256 + threadIdx.x;
    if (i < n) p[i] = 0;
}
__global__ void hist_kernel(const int* __restrict__ dst, int* counts, int E) {
    int e = blockIdx.x * 256 + threadIdx.x;
    if (e < E) atomicAdd(&counts[dst[e]], 1);
}
__global__ __launch_bounds__(1024) void scan_kernel(const int* __restrict__ counts,
                                                    int* __restrict__ off, int n) {
    __shared__ int sums[1024];
    int t = threadIdx.x;
    int chunk = (n + 1023) / 1024;
    int base = t * chunk;
    int s = 0;
    for (int i = 0; i < chunk; ++i) {
        int idx = base + i;
        if (idx < n) s += counts[idx];
    }
    sums[t] = s;
    __syncthreads();
    for (int d = 1; d < 1024; d <<= 1) {
        int v = (t >= d) ? sums[t - d] : 0;
        __syncthreads();
        sums[t] += v;
        __syncthreads();
    }
    int pre = (t == 0) ? 0 : sums[t - 1];
    for (int i = 0; i < chunk; ++i) {
        int idx = base + i;
        if (idx < n) { off[idx] = pre; pre += counts[idx]; }
    }
    if (t == 1023) off[n] = pre;
}
__global__ void scatter_kernel(const int* __restrict__ src, const int* __restrict__ dst,
                               const int* __restrict__ off, int* cursor,
                               int* __restrict__ eperm, int* __restrict__ srcp, int E) {
    int e = blockIdx.x * 256 + threadIdx.x;
    if (e < E) {
        int d = dst[e];
        int slot = atomicAdd(&cursor[d], 1);
        int p = off[d] + slot;
        eperm[p] = e;
        srcp[p] = src[e];
    }
}

// ---------------- node GEMM (f32 VALU) ------------------
template<bool ADD2, bool PREACT, bool BIAS>
__global__ __launch_bounds__(256) void node_gemm(
    const float* A, const float* A2,
    const float* __restrict__ WT, const float* __restrict__ bias,
    float* out, int n_rows)
{
    __shared__ float wt[128 * 128];
    __shared__ float at[32 * 128];
    const int tid = threadIdx.x;
    const int n0 = blockIdx.x * 32;

    #pragma unroll
    for (int t = 0; t < 16; ++t) {
        int f = tid + t * 256;
        *(float4*)&wt[f * 4] = ((const float4*)WT)[f];
    }
    #pragma unroll
    for (int t = 0; t < 4; ++t) {
        int f = tid + t * 256;
        int row = f >> 5, c4 = f & 31;
        float4 v = make_float4(0.f, 0.f, 0.f, 0.f);
        if (n0 + row < n_rows) {
            v = ((const float4*)A)[(size_t)(n0 + row) * 32 + c4];
            if (ADD2) {
                float4 w = ((const float4*)A2)[(size_t)(n0 + row) * 32 + c4];
                v.x += w.x; v.y += w.y; v.z += w.z; v.w += w.w;
            }
            if (PREACT) {
                v.x = ssp_fast(v.x); v.y = ssp_fast(v.y);
                v.z = ssp_fast(v.z); v.w = ssp_fast(v.w);
            }
        }
        *(float4*)&at[row * 128 + c4 * 4] = v;
    }
    __syncthreads();

    const int c = tid & 31, rg = tid >> 5;
    const int o0 = c * 4, r0 = rg * 4;
    float acc[4][4];
    #pragma unroll
    for (int i = 0; i < 4; ++i)
        #pragma unroll
        for (int j = 0; j < 4; ++j) acc[i][j] = 0.f;

    #pragma unroll 4
    for (int k = 0; k < 128; ++k) {
        float4 wv = *(const float4*)&wt[k * 128 + o0];
        #pragma unroll
        for (int i = 0; i < 4; ++i) {
            float a = at[(r0 + i) * 128 + k];
            acc[i][0] += a * wv.x; acc[i][1] += a * wv.y;
            acc[i][2] += a * wv.z; acc[i][3] += a * wv.w;
        }
    }

    float4 bv = make_float4(0.f, 0.f, 0.f, 0.f);
    if (BIAS) bv = ((const float4*)bias)[c];
    #pragma unroll
    for (int i = 0; i < 4; ++i) {
        int n = n0 + r0 + i;
        if (n < n_rows) {
            ((float4*)out)[(size_t)n * 32 + c] = make_float4(
                acc[i][0] + bv.x, acc[i][1] + bv.y, acc[i][2] + bv.z, acc[i][3] + bv.w);
        }
    }
}

// ---------------- edge MLP via bf16 MFMA (transposed outputs) --------------
// 1024 thr = 16 waves (4 out-groups x 4 edge-groups); 256 CSR edges/block.
// All GEMMs computed as D[out][edge] = W * act^T : A-frag = weights,
// B-frag = activations; lane holds edge = col (lane&15), 4 consecutive outs.
__global__ __launch_bounds__(1024, 4) void edge_mfma(
    const int* __restrict__ eperm, const float* __restrict__ ea,
    const float* __restrict__ ew,
    const ushort_t* __restrict__ w0b, const ushort_t* __restrict__ w2b,
    const float* __restrict__ b0g, const float* __restrict__ b2g,
    ushort_t* __restrict__ msg, int pos_base, int pos_end)
{
    __shared__ ushort_t ea_s[256 * 64];    // 32 KB, swizzled rows
    __shared__ ushort_t u_s [256 * 128];   // 64 KB, swizzled rows
    __shared__ ushort_t w0s [128 * 64];    // 16 KB (pre-swizzled in global)
    __shared__ ushort_t w2s [128 * 128];   // 32 KB (pre-swizzled in global)
    __shared__ float    cws [256];

    const int tid = threadIdx.x;
    const int p0 = pos_base + blockIdx.x * 256;

    // ---- staging ----
    ((us8*)w0s)[tid] = ((const us8*)w0b)[tid];
    ((us8*)w2s)[tid]        = ((const us8*)w2b)[tid];
    ((us8*)w2s)[tid + 1024] = ((const us8*)w2b)[tid + 1024];
    {
        int r   = tid >> 2;          // 0..255 edge row
        int cc0 = (tid & 3) * 2;     // chunk pair {cc0, cc0+1}, 8 elems each
        int pos = p0 + r;
        float2 vals[8];
        #pragma unroll
        for (int q = 0; q < 8; ++q) vals[q] = make_float2(0.f, 0.f);
        if (pos < pos_end) {
            int e = eperm[pos];
            const float2* rp = (const float2*)(ea + (size_t)e * 50);
            #pragma unroll
            for (int q = 0; q < 8; ++q) {
                int f2i = cc0 * 4 + q;
                if (f2i < 25) vals[q] = rp[f2i];
            }
        }
        #pragma unroll
        for (int half = 0; half < 2; ++half) {
            int c = cc0 + half;
            us8 v;
            #pragma unroll
            for (int q = 0; q < 4; ++q) {
                float2 f = vals[half * 4 + q];
                v[2 * q]     = f2bf(f.x);
                v[2 * q + 1] = f2bf(f.y);
            }
            *(us8*)&ea_s[r * 64 + ((c * 8) ^ ((r & 7) << 3))] = v;
        }
    }
    if (tid < 256) {
        int pos = p0 + tid;
        float cv = 0.f;
        if (pos < pos_end) {
            int e = eperm[pos];
            cv = 0.5f * (__builtin_amdgcn_cosf(ew[e] * 0.05f) + 1.0f);
        }
        cws[tid] = cv;
    }
    __syncthreads();

    const int lane = tid & 63;
    const int wid  = tid >> 6;
    const int out0w = (wid >> 2) * 32;   // 4 out-groups of 32
    const int e0w   = (wid & 3) * 64;    // 4 edge-groups of 64
    const int lm = lane & 15;
    const int lh = lane >> 4;

    // ---- GEMM1: t^T = w0 * ea^T  (K = 64 padded) ----
    f32x4 acc1[2][4];
    #pragma unroll
    for (int mt = 0; mt < 2; ++mt)
        #pragma unroll
        for (int nt = 0; nt < 4; ++nt) acc1[mt][nt] = (f32x4){0.f, 0.f, 0.f, 0.f};

    #pragma unroll
    for (int ks = 0; ks < 2; ++ks) {
        int k8 = ks * 32 + lh * 8;
        bf16x8 aw[2];
        #pragma unroll
        for (int mt = 0; mt < 2; ++mt) {
            int n = out0w + mt * 16 + lm;
            aw[mt] = __builtin_bit_cast(bf16x8,
                *(const us8*)&w0s[n * 64 + (k8 ^ ((n & 7) << 3))]);
        }
        #pragma unroll
        for (int nt = 0; nt < 4; ++nt) {
            int e = e0w + nt * 16 + lm;
            bf16x8 be = __builtin_bit_cast(bf16x8,
                *(const us8*)&ea_s[e * 64 + (k8 ^ ((e & 7) << 3))]);
            #pragma unroll
            for (int mt = 0; mt < 2; ++mt)
                acc1[mt][nt] = __builtin_amdgcn_mfma_f32_16x16x32_bf16(
                    aw[mt], be, acc1[mt][nt], 0, 0, 0);
        }
    }

    // epilogue1: u = ssp(t + b0) -> packed 4xbf16 ds_write_b64
    #pragma unroll
    for (int mt = 0; mt < 2; ++mt) {
        int out0 = out0w + mt * 16 + lh * 4;
        f32x4 b0v = *(const f32x4*)&b0g[out0];
        #pragma unroll
        for (int nt = 0; nt < 4; ++nt) {
            int e = e0w + nt * 16 + lm;
            us4 pk;
            #pragma unroll
            for (int j = 0; j < 4; ++j)
                pk[j] = f2bf(ssp_fast(acc1[mt][nt][j] + b0v[j]));
            *(us4*)&u_s[e * 128 + (out0 ^ ((e & 7) << 3))] = pk;
        }
    }
    __syncthreads();

    // ---- GEMM2: W^T = w2 * u^T  (K = 128) ----
    f32x4 acc2[2][4];
    #pragma unroll
    for (int mt = 0; mt < 2; ++mt)
        #pragma unroll
        for (int nt = 0; nt < 4; ++nt) acc2[mt][nt] = (f32x4){0.f, 0.f, 0.f, 0.f};

    #pragma unroll
    for (int ks = 0; ks < 4; ++ks) {
        int k8 = ks * 32 + lh * 8;
        bf16x8 aw[2];
        #pragma unroll
        for (int mt = 0; mt < 2; ++mt) {
            int n = out0w + mt * 16 + lm;
            aw[mt] = __builtin_bit_cast(bf16x8,
                *(const us8*)&w2s[n * 128 + (k8 ^ ((n & 7) << 3))]);
        }
        #pragma unroll
        for (int nt = 0; nt < 4; ++nt) {
            int e = e0w + nt * 16 + lm;
            bf16x8 be = __builtin_bit_cast(bf16x8,
                *(const us8*)&u_s[e * 128 + (k8 ^ ((e & 7) << 3))]);
            #pragma unroll
            for (int mt = 0; mt < 2; ++mt)
                acc2[mt][nt] = __builtin_amdgcn_mfma_f32_16x16x32_bf16(
                    aw[mt], be, acc2[mt][nt], 0, 0, 0);
        }
    }

    // epilogue2: msg[pos][out] = c * (W + b2), packed 8B stores
    #pragma unroll
    for (int mt = 0; mt < 2; ++mt) {
        int out0 = out0w + mt * 16 + lh * 4;
        f32x4 b2v = *(const f32x4*)&b2g[out0];
        #pragma unroll
        for (int nt = 0; nt < 4; ++nt) {
            int e = e0w + nt * 16 + lm;
            int pos = p0 + e;
            if (pos < pos_end) {
                float cv = cws[e];
                us4 pk;
                #pragma unroll
                for (int j = 0; j < 4; ++j)
                    pk[j] = f2bf(cv * (acc2[mt][nt][j] + b2v[j]));
                *(us4*)&msg[(size_t)(pos - pos_base) * 128 + out0] = pk;
            }
        }
    }
}

// ---------------- aggregation: one wave per dst node -----------------------
__global__ __launch_bounds__(256) void aggregate(
    const int* __restrict__ off, const int* __restrict__ srcp,
    const ushort_t* __restrict__ msg, const float* __restrict__ h1,
    float* __restrict__ agg, int n_nodes, int clo, int chi, int first)
{
    int wid = threadIdx.x >> 6, lane = threadIdx.x & 63;
    int d = blockIdx.x * 4 + wid;
    if (d >= n_nodes) return;
    int p0 = max(off[d], clo);
    int p1 = min(off[d + 1], chi);
    int ch = lane * 2;
    float ax = 0.f, ay = 0.f;
    if (!first) {
        float2 v = *(const float2*)&agg[(size_t)d * 128 + ch];
        ax = v.x; ay = v.y;
    }
    for (int p = p0; p < p1; ++p) {
        int s = srcp[p];
        unsigned mm = *(const unsigned*)&msg[(size_t)(p - clo) * 128 + ch];
        float2 hv = *(const float2*)&h1[(size_t)s * 128 + ch];
        ax += bf2f((ushort_t)(mm & 0xffffu)) * hv.x;
        ay += bf2f((ushort_t)(mm >> 16)) * hv.y;
    }
    *(float2*)&agg[(size_t)d * 128 + ch] = make_float2(ax, ay);
}

extern "C" void kernel_launch(void* const* d_in, const int* in_sizes, int n_in,
                              void* d_out, int out_size, void* d_ws, size_t ws_size,
                              hipStream_t stream) {
    const float* h       = (const float*)d_in[0];
    const int*   ei      = (const int*)  d_in[1];
    const float* ew      = (const float*)d_in[2];
    const float* ea      = (const float*)d_in[3];
    const float* mlp_w0  = (const float*)d_in[4];
    const float* mlp_b0  = (const float*)d_in[5];
    const float* mlp_w2  = (const float*)d_in[6];
    const float* mlp_b2  = (const float*)d_in[7];
    const float* lin1_w  = (const float*)d_in[8];
    const float* lin2_w  = (const float*)d_in[9];
    const float* lin2_b  = (const float*)d_in[10];
    const float* lin_w   = (const float*)d_in[11];
    const float* lin_b   = (const float*)d_in[12];
    float* out = (float*)d_out;
    float* ws  = (float*)d_ws;

    const int N = in_sizes[0] / HID;       // 50000
    const int E = in_sizes[2];             // 600000
    const int NODE_PAD = ((N + 1) + 175) / 176 * 176;
    const int CH = (E + 1) / 2;                          // 300000 (2 chunks)
    const int CH_ROWS = (CH + 255) & ~255;

    float* h1   = ws;                                   // N*128
    float* agg  = h1  + (size_t)N * 128;                // N*128
    float* wt1  = agg + (size_t)N * 128;                // 16384
    float* wt2  = wt1 + 16384;
    float* wtf  = wt2 + 16384;
    ushort_t* w0b = (ushort_t*)(wtf + 16384);           // 8192 u16
    ushort_t* w2b = (ushort_t*)((float*)w0b + 4096);    // 16384 u16
    int* counts = (int*)((float*)w0b + 4096 + 8192);
    int* off    = counts + NODE_PAD;
    int* cursor = off + NODE_PAD;
    int* eperm  = cursor + NODE_PAD;
    int* srcp   = eperm + E;
    ushort_t* msg = (ushort_t*)(srcp + E);              // CH_ROWS*128 u16

    const int* srcI = ei;
    const int* dstI = ei + E;

    prep_weights<<<288, 256, 0, stream>>>(lin1_w, lin2_w, lin_w, mlp_w0, mlp_w2,
                                          wt1, wt2, wtf, w0b, w2b);

    zero_ints<<<(2 * NODE_PAD + 255) / 256, 256, 0, stream>>>(counts, 2 * NODE_PAD);
    zero_ints<<<(NODE_PAD + 255) / 256, 256, 0, stream>>>(cursor, NODE_PAD);
    hist_kernel<<<(E + 255) / 256, 256, 0, stream>>>(dstI, counts, E);
    scan_kernel<<<1, 1024, 0, stream>>>(counts, off, N);
    scatter_kernel<<<(E + 255) / 256, 256, 0, stream>>>(srcI, dstI, off, cursor,
                                                        eperm, srcp, E);

    int ngrid = (N + 31) / 32;
    node_gemm<false, false, false><<<ngrid, 256, 0, stream>>>(h, nullptr, wt1,
                                                              nullptr, h1, N);

    int aggrid = (N + 3) / 4;
    for (int c = 0; c < 2; ++c) {
        int clo = c * CH;
        int chi = min(E, clo + CH);
        if (chi <= clo) break;
        int nblk = (chi - clo + 255) / 256;
        edge_mfma<<<nblk, 1024, 0, stream>>>(eperm, ea, ew, w0b, w2b,
                                             mlp_b0, mlp_b2, msg, clo, chi);
        aggregate<<<aggrid, 256, 0, stream>>>(off, srcp, msg, h1, agg, N,
                                              clo, chi, c == 0);
    }

    node_gemm<true, false, true><<<ngrid, 256, 0, stream>>>(h1, agg, wt2,
                                                            lin2_b, h1, N);
    node_gemm<false, true, true><<<ngrid, 256, 0, stream>>>(h1, nullptr, wtf,
                                                            lin_b, out, N);
}

// Round 4
// 478.589 us; speedup vs baseline: 2.9275x; 1.1162x over previous
//
#include <hip/hip_runtime.h>
#include <math.h>

#define HID 128
#define NF  128
#define NG  50

typedef unsigned short ushort_t;
typedef unsigned short us8 __attribute__((ext_vector_type(8)));
typedef unsigned short us4 __attribute__((ext_vector_type(4)));
typedef __bf16 bf16x8 __attribute__((ext_vector_type(8)));
typedef float f32x4 __attribute__((ext_vector_type(4)));

__device__ inline float ssp_fast(float x) {
    // softplus(x) - ln2 = max(x,0) + ln2*(log2(1+exp2(-|x|*log2e)) - 1)
    float t = __builtin_amdgcn_exp2f(fabsf(x) * -1.4426950408889634f);
    float l = __builtin_amdgcn_logf(1.0f + t);      // log2
    return fmaxf(x, 0.0f) + 0.6931471805599453f * (l - 1.0f);
}

__device__ inline ushort_t f2bf(float f) {
    unsigned u = __builtin_bit_cast(unsigned, f);
    unsigned r = (u + 0x7fffu + ((u >> 16) & 1u)) >> 16;
    return (ushort_t)r;
}
__device__ inline float bf2f(ushort_t h) {
    unsigned u = ((unsigned)h) << 16;
    return __builtin_bit_cast(float, u);
}

// ---------------- weight prep: f32 transposes + bf16 pre-swizzled ----------
// swizzle: element (row o, col k) stored at k ^ ((o&7)<<3)
__global__ void prep_weights(const float* __restrict__ lin1_w,
                             const float* __restrict__ lin2_w,
                             const float* __restrict__ lin_w,
                             const float* __restrict__ mlp_w0,
                             const float* __restrict__ mlp_w2,
                             float* __restrict__ wt1,
                             float* __restrict__ wt2,
                             float* __restrict__ wtf,
                             ushort_t* __restrict__ w0b,
                             ushort_t* __restrict__ w2b) {
    int idx = blockIdx.x * 256 + threadIdx.x;
    if (idx < 49152) {
        int m = idx >> 14, i = idx & 16383;
        int r = i >> 7, c = i & 127;
        const float* s = (m == 0) ? lin1_w : (m == 1) ? lin2_w : lin_w;
        float*       d = (m == 0) ? wt1    : (m == 1) ? wt2    : wtf;
        d[c * 128 + r] = s[i];
    } else if (idx < 49152 + 8192) {
        int i = idx - 49152;            // o*64 + k
        int o = i >> 6, k = i & 63;
        float v = (k < 50) ? mlp_w0[o * 50 + k] : 0.f;
        w0b[o * 64 + (k ^ ((o & 7) << 3))] = f2bf(v);
    } else if (idx < 49152 + 8192 + 16384) {
        int i = idx - 57344;            // o*128 + k
        int o = i >> 7, k = i & 127;
        w2b[o * 128 + (k ^ ((o & 7) << 3))] = f2bf(mlp_w2[i]);
    }
}

// ---------------- CSR build ----------------
__global__ void hist_kernel(const int* __restrict__ dst, int* counts, int E) {
    int e = blockIdx.x * 256 + threadIdx.x;
    if (e < E) atomicAdd(&counts[dst[e]], 1);
}
__global__ __launch_bounds__(1024) void scan_kernel(const int* __restrict__ counts,
                                                    int* __restrict__ off, int n) {
    __shared__ int sums[1024];
    int t = threadIdx.x;
    int chunk = (n + 1023) / 1024;
    int base = t * chunk;
    int s = 0;
    for (int i = 0; i < chunk; ++i) {
        int idx = base + i;
        if (idx < n) s += counts[idx];
    }
    sums[t] = s;
    __syncthreads();
    for (int d = 1; d < 1024; d <<= 1) {
        int v = (t >= d) ? sums[t - d] : 0;
        __syncthreads();
        sums[t] += v;
        __syncthreads();
    }
    int pre = (t == 0) ? 0 : sums[t - 1];
    for (int i = 0; i < chunk; ++i) {
        int idx = base + i;
        if (idx < n) { off[idx] = pre; pre += counts[idx]; }
    }
    if (t == 1023) off[n] = pre;
}
__global__ void scatter_kernel(const int* __restrict__ src, const int* __restrict__ dst,
                               const int* __restrict__ off, int* cursor,
                               int* __restrict__ eperm, int* __restrict__ srcp,
                               int* __restrict__ dstp, int E) {
    int e = blockIdx.x * 256 + threadIdx.x;
    if (e < E) {
        int d = dst[e];
        int slot = atomicAdd(&cursor[d], 1);
        int p = off[d] + slot;
        eperm[p] = e;
        srcp[p] = src[e];
        dstp[p] = d;
    }
}

// ---------------- permute+convert ea to CSR order, pre-swizzled bf16 -------
// 8 lanes per position row; also cwp; pads [E, PADE) with zeros.
__global__ __launch_bounds__(256) void permute_ea(
    const int* __restrict__ eperm, const float* __restrict__ ea,
    const float* __restrict__ ew, ushort_t* __restrict__ eab,
    float* __restrict__ cwp, int* __restrict__ srcp, int* __restrict__ dstp,
    int E, int PADE)
{
    int t = blockIdx.x * 256 + threadIdx.x;
    int p = t >> 3, q = t & 7;
    if (p >= PADE) return;
    us8 v = {0, 0, 0, 0, 0, 0, 0, 0};
    if (p < E) {
        int e = eperm[p];
        const float* row = ea + (size_t)e * 50;
        #pragma unroll
        for (int j = 0; j < 4; ++j) {
            int col = q * 8 + j * 2;
            if (col < 50) {
                float2 f = *(const float2*)(row + col);
                v[2 * j]     = f2bf(f.x);
                v[2 * j + 1] = f2bf(f.y);
            }
        }
        if (q == 0)
            cwp[p] = 0.5f * (__builtin_amdgcn_cosf(ew[e] * 0.05f) + 1.0f);
    } else if (q == 0) {
        cwp[p] = 0.f; srcp[p] = 0; dstp[p] = 0;
    }
    *(us8*)&eab[(size_t)p * 64 + ((q * 8) ^ ((p & 7) << 3))] = v;
}

// ---------------- node GEMM (f32 VALU) ------------------
template<bool ADD2, bool PREACT, bool BIAS, bool H1B>
__global__ __launch_bounds__(256) void node_gemm(
    const float* A, const float* A2,
    const float* __restrict__ WT, const float* __restrict__ bias,
    float* out, ushort_t* outb, int n_rows)
{
    __shared__ float wt[128 * 128];
    __shared__ float at[32 * 128];
    const int tid = threadIdx.x;
    const int n0 = blockIdx.x * 32;

    #pragma unroll
    for (int t = 0; t < 16; ++t) {
        int f = tid + t * 256;
        *(float4*)&wt[f * 4] = ((const float4*)WT)[f];
    }
    #pragma unroll
    for (int t = 0; t < 4; ++t) {
        int f = tid + t * 256;
        int row = f >> 5, c4 = f & 31;
        float4 v = make_float4(0.f, 0.f, 0.f, 0.f);
        if (n0 + row < n_rows) {
            v = ((const float4*)A)[(size_t)(n0 + row) * 32 + c4];
            if (ADD2) {
                float4 w = ((const float4*)A2)[(size_t)(n0 + row) * 32 + c4];
                v.x += w.x; v.y += w.y; v.z += w.z; v.w += w.w;
            }
            if (PREACT) {
                v.x = ssp_fast(v.x); v.y = ssp_fast(v.y);
                v.z = ssp_fast(v.z); v.w = ssp_fast(v.w);
            }
        }
        *(float4*)&at[row * 128 + c4 * 4] = v;
    }
    __syncthreads();

    const int c = tid & 31, rg = tid >> 5;
    const int o0 = c * 4, r0 = rg * 4;
    float acc[4][4];
    #pragma unroll
    for (int i = 0; i < 4; ++i)
        #pragma unroll
        for (int j = 0; j < 4; ++j) acc[i][j] = 0.f;

    #pragma unroll 4
    for (int k = 0; k < 128; ++k) {
        float4 wv = *(const float4*)&wt[k * 128 + o0];
        #pragma unroll
        for (int i = 0; i < 4; ++i) {
            float a = at[(r0 + i) * 128 + k];
            acc[i][0] += a * wv.x; acc[i][1] += a * wv.y;
            acc[i][2] += a * wv.z; acc[i][3] += a * wv.w;
        }
    }

    float4 bv = make_float4(0.f, 0.f, 0.f, 0.f);
    if (BIAS) bv = ((const float4*)bias)[c];
    #pragma unroll
    for (int i = 0; i < 4; ++i) {
        int n = n0 + r0 + i;
        if (n < n_rows) {
            float4 v = make_float4(acc[i][0] + bv.x, acc[i][1] + bv.y,
                                   acc[i][2] + bv.z, acc[i][3] + bv.w);
            ((float4*)out)[(size_t)n * 32 + c] = v;
            if (H1B) {
                us4 pk;
                pk[0] = f2bf(v.x); pk[1] = f2bf(v.y);
                pk[2] = f2bf(v.z); pk[3] = f2bf(v.w);
                *(us4*)&outb[(size_t)n * 128 + o0] = pk;
            }
        }
    }
}

// ---------------- fused edge MLP + message + segmented aggregation ---------
// 1024 thr = 16 waves (4 out-groups x 4 edge-groups); 256 CSR positions/block.
// D[out][edge] layout: lane holds edge=(lane&15), 4 consecutive outs.
__global__ __launch_bounds__(1024, 4) void edge_fused(
    const ushort_t* __restrict__ eab, const float* __restrict__ cwp,
    const int* __restrict__ srcp, const int* __restrict__ dstp,
    const ushort_t* __restrict__ w0b, const ushort_t* __restrict__ w2b,
    const float* __restrict__ b0g, const float* __restrict__ b2g,
    const ushort_t* __restrict__ h1b, float* __restrict__ agg)
{
    __shared__ __align__(16) char blob[150528];
    ushort_t* ea_s = (ushort_t*)blob;                 // 32 KB
    ushort_t* w0s  = (ushort_t*)(blob + 32768);       // 16 KB
    ushort_t* w2s  = (ushort_t*)(blob + 49152);       // 32 KB
    ushort_t* u_s  = (ushort_t*)(blob + 81920);       // 64 KB
    float*    m_s  = (float*)blob;                    // 128 KB overlay (phase D/E)
    float* cws  = (float*)(blob + 147456);            // 1 KB
    int*   srcs = (int*)(blob + 148480);              // 1 KB
    int*   dsts = (int*)(blob + 149504);              // 1 KB

    const int tid = threadIdx.x;
    const int p0 = blockIdx.x * 256;

    // ---- phase A: staging (all linear; swizzle already applied in global) --
    {
        const us8* eg = (const us8*)(eab + (size_t)p0 * 64);
        ((us8*)ea_s)[tid]        = eg[tid];
        ((us8*)ea_s)[tid + 1024] = eg[tid + 1024];
        ((us8*)w0s)[tid]         = ((const us8*)w0b)[tid];
        ((us8*)w2s)[tid]         = ((const us8*)w2b)[tid];
        ((us8*)w2s)[tid + 1024]  = ((const us8*)w2b)[tid + 1024];
        if (tid < 256) {
            cws[tid]  = cwp[p0 + tid];
            srcs[tid] = srcp[p0 + tid];
            dsts[tid] = dstp[p0 + tid];
        }
    }
    __syncthreads();

    const int lane = tid & 63;
    const int wid  = tid >> 6;
    const int out0w = (wid >> 2) * 32;   // 4 out-groups of 32
    const int e0w   = (wid & 3) * 64;    // 4 edge-groups of 64
    const int lm = lane & 15;
    const int lh = lane >> 4;

    // early h1b gather (hidden under the two GEMMs)
    float cv[4]; int sv[4];
    #pragma unroll
    for (int nt = 0; nt < 4; ++nt) {
        int e = e0w + nt * 16 + lm;
        cv[nt] = cws[e];
        sv[nt] = srcs[e];
    }
    us4 h1v[2][4];
    #pragma unroll
    for (int mt = 0; mt < 2; ++mt) {
        int out0 = out0w + mt * 16 + lh * 4;
        #pragma unroll
        for (int nt = 0; nt < 4; ++nt)
            h1v[mt][nt] = *(const us4*)&h1b[(size_t)sv[nt] * 128 + out0];
    }

    // ---- GEMM1: t^T = w0 * ea^T  (K = 64 padded) ----
    f32x4 acc1[2][4];
    #pragma unroll
    for (int mt = 0; mt < 2; ++mt)
        #pragma unroll
        for (int nt = 0; nt < 4; ++nt) acc1[mt][nt] = (f32x4){0.f, 0.f, 0.f, 0.f};

    #pragma unroll
    for (int ks = 0; ks < 2; ++ks) {
        int k8 = ks * 32 + lh * 8;
        bf16x8 aw[2];
        #pragma unroll
        for (int mt = 0; mt < 2; ++mt) {
            int n = out0w + mt * 16 + lm;
            aw[mt] = __builtin_bit_cast(bf16x8,
                *(const us8*)&w0s[n * 64 + (k8 ^ ((n & 7) << 3))]);
        }
        #pragma unroll
        for (int nt = 0; nt < 4; ++nt) {
            int e = e0w + nt * 16 + lm;
            bf16x8 be = __builtin_bit_cast(bf16x8,
                *(const us8*)&ea_s[e * 64 + (k8 ^ ((e & 7) << 3))]);
            #pragma unroll
            for (int mt = 0; mt < 2; ++mt)
                acc1[mt][nt] = __builtin_amdgcn_mfma_f32_16x16x32_bf16(
                    aw[mt], be, acc1[mt][nt], 0, 0, 0);
        }
    }

    // epilogue1: u = ssp(t + b0) -> packed 4xbf16 ds_write_b64
    #pragma unroll
    for (int mt = 0; mt < 2; ++mt) {
        int out0 = out0w + mt * 16 + lh * 4;
        f32x4 b0v = *(const f32x4*)&b0g[out0];
        #pragma unroll
        for (int nt = 0; nt < 4; ++nt) {
            int e = e0w + nt * 16 + lm;
            us4 pk;
            #pragma unroll
            for (int j = 0; j < 4; ++j)
                pk[j] = f2bf(ssp_fast(acc1[mt][nt][j] + b0v[j]));
            *(us4*)&u_s[e * 128 + (out0 ^ ((e & 7) << 3))] = pk;
        }
    }
    __syncthreads();

    // ---- GEMM2: W^T = w2 * u^T  (K = 128) ----
    f32x4 acc2[2][4];
    #pragma unroll
    for (int mt = 0; mt < 2; ++mt)
        #pragma unroll
        for (int nt = 0; nt < 4; ++nt) acc2[mt][nt] = (f32x4){0.f, 0.f, 0.f, 0.f};

    #pragma unroll
    for (int ks = 0; ks < 4; ++ks) {
        int k8 = ks * 32 + lh * 8;
        bf16x8 aw[2];
        #pragma unroll
        for (int mt = 0; mt < 2; ++mt) {
            int n = out0w + mt * 16 + lm;
            aw[mt] = __builtin_bit_cast(bf16x8,
                *(const us8*)&w2s[n * 128 + (k8 ^ ((n & 7) << 3))]);
        }
        #pragma unroll
        for (int nt = 0; nt < 4; ++nt) {
            int e = e0w + nt * 16 + lm;
            bf16x8 be = __builtin_bit_cast(bf16x8,
                *(const us8*)&u_s[e * 128 + (k8 ^ ((e & 7) << 3))]);
            #pragma unroll
            for (int mt = 0; mt < 2; ++mt)
                acc2[mt][nt] = __builtin_amdgcn_mfma_f32_16x16x32_bf16(
                    aw[mt], be, acc2[mt][nt], 0, 0, 0);
        }
    }
    __syncthreads();    // all u_s/ea_s/w*_s reads done; m_s overlay now safe

    // ---- phase D: m = c * (W + b2) * h1[src]  -> f32 LDS (swizzled) ----
    #pragma unroll
    for (int mt = 0; mt < 2; ++mt) {
        int out0 = out0w + mt * 16 + lh * 4;
        f32x4 b2v = *(const f32x4*)&b2g[out0];
        #pragma unroll
        for (int nt = 0; nt < 4; ++nt) {
            int e = e0w + nt * 16 + lm;
            f32x4 mv;
            #pragma unroll
            for (int j = 0; j < 4; ++j)
                mv[j] = cv[nt] * (acc2[mt][nt][j] + b2v[j]) * bf2f(h1v[mt][nt][j]);
            *(f32x4*)&m_s[e * 128 + (out0 ^ ((e & 7) << 2))] = mv;
        }
    }
    __syncthreads();

    // ---- phase E: segmented reduce by dst, flush via f32 atomics ----
    {
        const int ch = tid & 127;
        const int i0 = (tid >> 7) * 32;
        float sum = 0.f;
        int prev = dsts[i0];
        #pragma unroll 4
        for (int i = i0; i < i0 + 32; ++i) {
            int d = dsts[i];
            float v = m_s[i * 128 + (ch ^ ((i & 7) << 2))];
            if (d != prev) {
                atomicAdd(&agg[(size_t)prev * 128 + ch], sum);
                sum = 0.f; prev = d;
            }
            sum += v;
        }
        atomicAdd(&agg[(size_t)prev * 128 + ch], sum);
    }
}

extern "C" void kernel_launch(void* const* d_in, const int* in_sizes, int n_in,
                              void* d_out, int out_size, void* d_ws, size_t ws_size,
                              hipStream_t stream) {
    const float* h       = (const float*)d_in[0];
    const int*   ei      = (const int*)  d_in[1];
    const float* ew      = (const float*)d_in[2];
    const float* ea      = (const float*)d_in[3];
    const float* mlp_w0  = (const float*)d_in[4];
    const float* mlp_b0  = (const float*)d_in[5];
    const float* mlp_w2  = (const float*)d_in[6];
    const float* mlp_b2  = (const float*)d_in[7];
    const float* lin1_w  = (const float*)d_in[8];
    const float* lin2_w  = (const float*)d_in[9];
    const float* lin2_b  = (const float*)d_in[10];
    const float* lin_w   = (const float*)d_in[11];
    const float* lin_b   = (const float*)d_in[12];
    float* out = (float*)d_out;
    float* ws  = (float*)d_ws;

    const int N = in_sizes[0] / HID;            // 50000
    const int E = in_sizes[2];                  // 600000
    const int PADE = (E + 255) & ~255;          // 600064
    const int NODE_PAD = (N + 256) & ~255;      // 50176 (>= N+1)

    // ---- workspace layout (f32 slots) ----
    float* h1    = ws;                                   // N*128
    float* agg   = h1 + (size_t)N * 128;                 // N*128
    ushort_t* h1b = (ushort_t*)(agg + (size_t)N * 128);  // N*128 us = N*64 f32
    float* wt1   = (float*)(h1b + (size_t)N * 128);
    float* wt2   = wt1 + 16384;
    float* wtf   = wt2 + 16384;
    ushort_t* w0b = (ushort_t*)(wtf + 16384);            // 8192 us = 4096 f32
    ushort_t* w2b = (ushort_t*)((float*)w0b + 4096);     // 16384 us = 8192 f32
    int* counts  = (int*)((float*)w0b + 4096 + 8192);    // NODE_PAD
    int* off     = counts + NODE_PAD;                    // NODE_PAD
    int* cursor  = off + NODE_PAD;                       // NODE_PAD
    int* eperm   = cursor + NODE_PAD;                    // E
    int* srcp    = eperm + E;                            // PADE
    int* dstp    = srcp + PADE;                          // PADE
    float* cwp   = (float*)(dstp + PADE);                // PADE
    ushort_t* eab = (ushort_t*)(cwp + PADE);             // PADE*64 us

    const int* srcI = ei;
    const int* dstI = ei + E;

    hipMemsetAsync(counts, 0, (size_t)NODE_PAD * 4, stream);
    hipMemsetAsync(cursor, 0, (size_t)NODE_PAD * 4, stream);
    hipMemsetAsync(agg, 0, (size_t)N * 128 * 4, stream);

    prep_weights<<<288, 256, 0, stream>>>(lin1_w, lin2_w, lin_w, mlp_w0, mlp_w2,
                                          wt1, wt2, wtf, w0b, w2b);

    hist_kernel<<<(E + 255) / 256, 256, 0, stream>>>(dstI, counts, E);
    scan_kernel<<<1, 1024, 0, stream>>>(counts, off, N);
    scatter_kernel<<<(E + 255) / 256, 256, 0, stream>>>(srcI, dstI, off, cursor,
                                                        eperm, srcp, dstp, E);
    permute_ea<<<PADE / 32, 256, 0, stream>>>(eperm, ea, ew, eab, cwp,
                                              srcp, dstp, E, PADE);

    // h1 = h @ lin1^T (+ bf16 copy for the gather)
    int ngrid = (N + 31) / 32;
    node_gemm<false, false, false, true><<<ngrid, 256, 0, stream>>>(
        h, nullptr, wt1, nullptr, h1, h1b, N);

    // fused edge MLP + message + aggregation
    edge_fused<<<PADE / 256, 1024, 0, stream>>>(eab, cwp, srcp, dstp,
                                                w0b, w2b, mlp_b0, mlp_b2,
                                                h1b, agg);

    // h2 = (h1 + agg) @ lin2^T + b2   (in-place into h1)
    node_gemm<true, false, true, false><<<ngrid, 256, 0, stream>>>(
        h1, agg, wt2, lin2_b, h1, nullptr, N);
    // out = ssp(h2) @ lin^T + lin_b
    node_gemm<false, true, true, false><<<ngrid, 256, 0, stream>>>(
        h1, nullptr, wtf, lin_b, out, nullptr, N);
}

// Round 5
// 286.116 us; speedup vs baseline: 4.8968x; 1.6727x over previous
//
#include <hip/hip_runtime.h>
#include <math.h>

#define HID 128
#define NF  128
#define NG  50

typedef unsigned short ushort_t;
typedef unsigned short us8 __attribute__((ext_vector_type(8)));
typedef unsigned short us4 __attribute__((ext_vector_type(4)));
typedef __bf16 bf16x8 __attribute__((ext_vector_type(8)));
typedef float f32x4 __attribute__((ext_vector_type(4)));

__device__ inline float ssp_fast(float x) {
    // softplus(x) - ln2 = max(x,0) + ln2*(log2(1+exp2(-|x|*log2e)) - 1)
    float t = __builtin_amdgcn_exp2f(fabsf(x) * -1.4426950408889634f);
    float l = __builtin_amdgcn_logf(1.0f + t);      // log2
    return fmaxf(x, 0.0f) + 0.6931471805599453f * (l - 1.0f);
}

__device__ inline ushort_t f2bf(float f) {
    return __builtin_bit_cast(ushort_t, (__bf16)f);   // v_cvt_pk_bf16_f32, RTNE
}
__device__ inline float bf2f(ushort_t h) {
    unsigned u = ((unsigned)h) << 16;
    return __builtin_bit_cast(float, u);
}

// async global->LDS, 16B per lane; LDS dest wave-uniform, global src per-lane
__device__ inline void gload16(const void* g, void* l) {
    __builtin_amdgcn_global_load_lds(
        (const __attribute__((address_space(1))) void*)g,
        (__attribute__((address_space(3))) void*)l, 16, 0, 0);
}

// ---------------- weight prep: all bf16, pre-swizzled -----------------------
// element (row o, col k) stored at k ^ ((o&7)<<3); lin* are [out][k] already.
__global__ void prep_weights(const float* __restrict__ lin1_w,
                             const float* __restrict__ lin2_w,
                             const float* __restrict__ lin_w,
                             const float* __restrict__ mlp_w0,
                             const float* __restrict__ mlp_w2,
                             ushort_t* __restrict__ l1b,
                             ushort_t* __restrict__ l2b,
                             ushort_t* __restrict__ lfb,
                             ushort_t* __restrict__ w0b,
                             ushort_t* __restrict__ w2b) {
    int idx = blockIdx.x * 256 + threadIdx.x;
    if (idx < 49152) {
        int m = idx >> 14, i = idx & 16383;
        int o = i >> 7, k = i & 127;
        const float* s = (m == 0) ? lin1_w : (m == 1) ? lin2_w : lin_w;
        ushort_t*    d = (m == 0) ? l1b    : (m == 1) ? l2b    : lfb;
        d[o * 128 + (k ^ ((o & 7) << 3))] = f2bf(s[i]);
    } else if (idx < 49152 + 8192) {
        int i = idx - 49152;            // o*64 + k
        int o = i >> 6, k = i & 63;
        float v = (k < 50) ? mlp_w0[o * 50 + k] : 0.f;
        w0b[o * 64 + (k ^ ((o & 7) << 3))] = f2bf(v);
    } else if (idx < 49152 + 8192 + 16384) {
        int i = idx - 57344;            // o*128 + k
        int o = i >> 7, k = i & 127;
        w2b[o * 128 + (k ^ ((o & 7) << 3))] = f2bf(mlp_w2[i]);
    }
}

// ---------------- CSR build -------------------------------------------------
__global__ void count_slots(const int* __restrict__ dst, int* counts,
                            int* __restrict__ slot, int E) {
    int e = blockIdx.x * 256 + threadIdx.x;
    if (e < E) slot[e] = atomicAdd(&counts[dst[e]], 1);
}
__global__ __launch_bounds__(1024) void scan1(const int* __restrict__ counts,
                                              int* __restrict__ off,
                                              int* __restrict__ bsum, int n) {
    __shared__ int s[1024];
    int t = threadIdx.x, g = blockIdx.x * 1024 + t;
    int c = (g < n) ? counts[g] : 0;
    s[t] = c;
    __syncthreads();
    for (int d = 1; d < 1024; d <<= 1) {
        int v = (t >= d) ? s[t - d] : 0;
        __syncthreads();
        s[t] += v;
        __syncthreads();
    }
    if (g < n) off[g] = s[t] - c;             // exclusive within block
    if (t == 1023) bsum[blockIdx.x] = s[1023];
}
__global__ void scan2(int* bsum, int nb) {
    __shared__ int s[64];
    int t = threadIdx.x;
    int v = (t < nb) ? bsum[t] : 0;
    s[t] = v;
    __syncthreads();
    for (int d = 1; d < 64; d <<= 1) {
        int u = (t >= d) ? s[t - d] : 0;
        __syncthreads();
        s[t] += u;
        __syncthreads();
    }
    if (t < nb) bsum[t] = s[t] - v;           // exclusive carries
}
__global__ __launch_bounds__(1024) void scan3(int* __restrict__ off,
                                              const int* __restrict__ bsum, int n) {
    int g = blockIdx.x * 1024 + threadIdx.x;
    if (g < n) off[g] += bsum[blockIdx.x];
}

// ---------------- permute: e-ordered read, p-scattered write ----------------
// 8 threads/edge; writes eab row (bf16, swizzled for its CSR slot) + eperm.
__global__ __launch_bounds__(256) void permute_ea2(
    const int* __restrict__ dstI, const int* __restrict__ slot,
    const int* __restrict__ off, const float* __restrict__ ea,
    ushort_t* __restrict__ eab, int* __restrict__ eperm, int E)
{
    int t = blockIdx.x * 256 + threadIdx.x;
    int e = t >> 3, q = t & 7;
    if (e >= E) return;
    int p = off[dstI[e]] + slot[e];
    const float* row = ea + (size_t)e * 50;
    us8 v = {0, 0, 0, 0, 0, 0, 0, 0};
    #pragma unroll
    for (int j = 0; j < 4; ++j) {
        int col = q * 8 + j * 2;
        if (col < 50) {
            float2 f = *(const float2*)(row + col);
            v[2 * j]     = f2bf(f.x);
            v[2 * j + 1] = f2bf(f.y);
        }
    }
    *(us8*)&eab[(size_t)p * 64 + ((q * 8) ^ ((p & 7) << 3))] = v;
    if (q == 0) eperm[p] = e;
}

// ---------------- node GEMM via bf16 MFMA -----------------------------------
// 1024 thr = 16 waves (4 out-groups x 4 row-groups); 128 rows x 128 outs.
// D[row][out]: A-frag = activation rows (M), B-frag = weights (N=outs);
// lane&15 = out -> coalesced stores.
template<bool ADD2, bool PREACT, bool BIAS, bool H1B>
__global__ __launch_bounds__(1024, 4) void gemm_mfma(
    const float* __restrict__ A, const float* __restrict__ A2,
    const ushort_t* __restrict__ Wb, const float* __restrict__ bias,
    float* __restrict__ outF, ushort_t* __restrict__ outB, int n_rows)
{
    __shared__ ushort_t a_s[128 * 128];   // 32 KB, swizzled rows
    __shared__ ushort_t w_s[128 * 128];   // 32 KB, pre-swizzled in global
    const int tid = threadIdx.x;
    const int n0 = blockIdx.x * 128;
    const int lane = tid & 63, wid = tid >> 6;

    // W staging: 32 x 1KB chunks via global_load_lds
    #pragma unroll
    for (int i = 0; i < 2; ++i) {
        int cid = wid * 2 + i;
        gload16(Wb + cid * 512 + lane * 8, w_s + cid * 512);
    }
    // A staging: thread t -> row r = t>>3, cols q*16..+15 (f32 -> bf16)
    {
        int r = tid >> 3, q = tid & 7;
        int n = n0 + r;
        float vals[16];
        if (n < n_rows) {
            #pragma unroll
            for (int j = 0; j < 4; ++j) {
                f32x4 v = ((const f32x4*)A)[(size_t)n * 32 + q * 4 + j];
                if (ADD2) v += ((const f32x4*)A2)[(size_t)n * 32 + q * 4 + j];
                #pragma unroll
                for (int x = 0; x < 4; ++x)
                    vals[j * 4 + x] = PREACT ? ssp_fast(v[x]) : v[x];
            }
        } else {
            #pragma unroll
            for (int x = 0; x < 16; ++x) vals[x] = 0.f;
        }
        int sw = (r & 7) << 3;
        #pragma unroll
        for (int hh = 0; hh < 2; ++hh) {
            us8 pk;
            #pragma unroll
            for (int x = 0; x < 8; ++x) pk[x] = f2bf(vals[hh * 8 + x]);
            *(us8*)&a_s[r * 128 + ((q * 16 + hh * 8) ^ sw)] = pk;
        }
    }
    __syncthreads();

    const int og = (wid >> 2) * 32;   // out-group
    const int rg = (wid & 3) * 32;    // row-group
    const int lm = lane & 15, lh = lane >> 4;

    f32x4 acc[2][2];
    #pragma unroll
    for (int mt = 0; mt < 2; ++mt)
        #pragma unroll
        for (int nt = 0; nt < 2; ++nt) acc[mt][nt] = (f32x4){0.f, 0.f, 0.f, 0.f};

    #pragma unroll
    for (int ks = 0; ks < 4; ++ks) {
        int k8 = ks * 32 + lh * 8;
        bf16x8 af[2], wf[2];
        #pragma unroll
        for (int mt = 0; mt < 2; ++mt) {
            int m = rg + mt * 16 + lm;
            af[mt] = __builtin_bit_cast(bf16x8,
                *(const us8*)&a_s[m * 128 + (k8 ^ ((m & 7) << 3))]);
        }
        #pragma unroll
        for (int nt = 0; nt < 2; ++nt) {
            int n = og + nt * 16 + lm;
            wf[nt] = __builtin_bit_cast(bf16x8,
                *(const us8*)&w_s[n * 128 + (k8 ^ ((n & 7) << 3))]);
        }
        #pragma unroll
        for (int mt = 0; mt < 2; ++mt)
            #pragma unroll
            for (int nt = 0; nt < 2; ++nt)
                acc[mt][nt] = __builtin_amdgcn_mfma_f32_16x16x32_bf16(
                    af[mt], wf[nt], acc[mt][nt], 0, 0, 0);
    }

    #pragma unroll
    for (int nt = 0; nt < 2; ++nt) {
        int outc = og + nt * 16 + lm;
        float bv = BIAS ? bias[outc] : 0.f;
        #pragma unroll
        for (int mt = 0; mt < 2; ++mt) {
            int rbase = rg + mt * 16 + lh * 4;
            #pragma unroll
            for (int j = 0; j < 4; ++j) {
                int n = n0 + rbase + j;
                if (n < n_rows) {
                    float v = acc[mt][nt][j] + bv;
                    outF[(size_t)n * 128 + outc] = v;
                    if (H1B) outB[(size_t)n * 128 + outc] = f2bf(v);
                }
            }
        }
    }
}

// ---------------- fused edge MLP + message + segmented aggregation ---------
// 1024 thr = 16 waves (4 out-groups x 4 edge-groups); 256 CSR positions/block.
__global__ __launch_bounds__(1024, 4) void edge_fused(
    const ushort_t* __restrict__ eab, const int* __restrict__ eperm,
    const int* __restrict__ srcI, const int* __restrict__ dstI,
    const float* __restrict__ ew,
    const ushort_t* __restrict__ w0b, const ushort_t* __restrict__ w2b,
    const float* __restrict__ b0g, const float* __restrict__ b2g,
    const ushort_t* __restrict__ h1b, float* __restrict__ agg, int n_edges)
{
    __shared__ __align__(16) char blob[150528];
    ushort_t* ea_s = (ushort_t*)blob;                 // 32 KB  [0, 32768)
    ushort_t* w0s  = (ushort_t*)(blob + 32768);       // 16 KB
    ushort_t* w2s  = (ushort_t*)(blob + 49152);       // 32 KB
    ushort_t* u_s  = (ushort_t*)(blob + 81920);       // 64 KB
    float*    m_s  = (float*)blob;                    // 128 KB overlay (D/E)
    float* cws  = (float*)(blob + 147456);
    int*   srcs = (int*)(blob + 148480);
    int*   dsts = (int*)(blob + 149504);

    const int tid = threadIdx.x;
    const int p0 = blockIdx.x * 256;
    const int lane = tid & 63, wid = tid >> 6;

    // ---- phase A: async staging, 80 x 1KB chunks (ea 32, w0 16, w2 32) ----
    #pragma unroll
    for (int i = 0; i < 5; ++i) {
        int cid = wid * 5 + i;
        const ushort_t* g;
        if (cid < 32)      g = eab + (size_t)p0 * 64 + cid * 512;
        else if (cid < 48) g = w0b + (cid - 32) * 512;
        else               g = w2b + (cid - 48) * 512;
        gload16(g + lane * 8, (ushort_t*)blob + cid * 512);
    }
    if (tid < 256) {
        int pos = p0 + tid;
        float cv = 0.f; int s = 0, d = 0;
        if (pos < n_edges) {
            int e = eperm[pos];
            s = srcI[e]; d = dstI[e];
            cv = 0.5f * (__builtin_amdgcn_cosf(ew[e] * 0.05f) + 1.0f);
        }
        cws[tid] = cv; srcs[tid] = s; dsts[tid] = d;
    }
    __syncthreads();

    const int out0w = (wid >> 2) * 32;   // 4 out-groups of 32
    const int e0w   = (wid & 3) * 64;    // 4 edge-groups of 64
    const int lm = lane & 15, lh = lane >> 4;

    // early h1b gather (hidden under the two GEMMs)
    float cv[4]; int sv[4];
    #pragma unroll
    for (int nt = 0; nt < 4; ++nt) {
        int e = e0w + nt * 16 + lm;
        cv[nt] = cws[e];
        sv[nt] = srcs[e];
    }
    us4 h1v[2][4];
    #pragma unroll
    for (int mt = 0; mt < 2; ++mt) {
        int out0 = out0w + mt * 16 + lh * 4;
        #pragma unroll
        for (int nt = 0; nt < 4; ++nt)
            h1v[mt][nt] = *(const us4*)&h1b[(size_t)sv[nt] * 128 + out0];
    }

    // ---- GEMM1: t^T = w0 * ea^T  (K = 64 padded) ----
    f32x4 acc1[2][4];
    #pragma unroll
    for (int mt = 0; mt < 2; ++mt)
        #pragma unroll
        for (int nt = 0; nt < 4; ++nt) acc1[mt][nt] = (f32x4){0.f, 0.f, 0.f, 0.f};

    #pragma unroll
    for (int ks = 0; ks < 2; ++ks) {
        int k8 = ks * 32 + lh * 8;
        bf16x8 aw[2];
        #pragma unroll
        for (int mt = 0; mt < 2; ++mt) {
            int n = out0w + mt * 16 + lm;
            aw[mt] = __builtin_bit_cast(bf16x8,
                *(const us8*)&w0s[n * 64 + (k8 ^ ((n & 7) << 3))]);
        }
        #pragma unroll
        for (int nt = 0; nt < 4; ++nt) {
            int e = e0w + nt * 16 + lm;
            bf16x8 be = __builtin_bit_cast(bf16x8,
                *(const us8*)&ea_s[e * 64 + (k8 ^ ((e & 7) << 3))]);
            #pragma unroll
            for (int mt = 0; mt < 2; ++mt)
                acc1[mt][nt] = __builtin_amdgcn_mfma_f32_16x16x32_bf16(
                    aw[mt], be, acc1[mt][nt], 0, 0, 0);
        }
    }

    // epilogue1: u = ssp(t + b0) -> packed 4xbf16 ds_write_b64
    #pragma unroll
    for (int mt = 0; mt < 2; ++mt) {
        int out0 = out0w + mt * 16 + lh * 4;
        f32x4 b0v = *(const f32x4*)&b0g[out0];
        #pragma unroll
        for (int nt = 0; nt < 4; ++nt) {
            int e = e0w + nt * 16 + lm;
            us4 pk;
            #pragma unroll
            for (int j = 0; j < 4; ++j)
                pk[j] = f2bf(ssp_fast(acc1[mt][nt][j] + b0v[j]));
            *(us4*)&u_s[e * 128 + (out0 ^ ((e & 7) << 3))] = pk;
        }
    }
    __syncthreads();

    // ---- GEMM2: W^T = w2 * u^T  (K = 128) ----
    f32x4 acc2[2][4];
    #pragma unroll
    for (int mt = 0; mt < 2; ++mt)
        #pragma unroll
        for (int nt = 0; nt < 4; ++nt) acc2[mt][nt] = (f32x4){0.f, 0.f, 0.f, 0.f};

    #pragma unroll
    for (int ks = 0; ks < 4; ++ks) {
        int k8 = ks * 32 + lh * 8;
        bf16x8 aw[2];
        #pragma unroll
        for (int mt = 0; mt < 2; ++mt) {
            int n = out0w + mt * 16 + lm;
            aw[mt] = __builtin_bit_cast(bf16x8,
                *(const us8*)&w2s[n * 128 + (k8 ^ ((n & 7) << 3))]);
        }
        #pragma unroll
        for (int nt = 0; nt < 4; ++nt) {
            int e = e0w + nt * 16 + lm;
            bf16x8 be = __builtin_bit_cast(bf16x8,
                *(const us8*)&u_s[e * 128 + (k8 ^ ((e & 7) << 3))]);
            #pragma unroll
            for (int mt = 0; mt < 2; ++mt)
                acc2[mt][nt] = __builtin_amdgcn_mfma_f32_16x16x32_bf16(
                    aw[mt], be, acc2[mt][nt], 0, 0, 0);
        }
    }
    __syncthreads();    // all u_s/ea_s/w*_s reads done; m_s overlay now safe

    // ---- phase D: m = c * (W + b2) * h1[src]  -> f32 LDS (swizzled) ----
    #pragma unroll
    for (int mt = 0; mt < 2; ++mt) {
        int out0 = out0w + mt * 16 + lh * 4;
        f32x4 b2v = *(const f32x4*)&b2g[out0];
        #pragma unroll
        for (int nt = 0; nt < 4; ++nt) {
            int e = e0w + nt * 16 + lm;
            f32x4 mv;
            #pragma unroll
            for (int j = 0; j < 4; ++j)
                mv[j] = cv[nt] * (acc2[mt][nt][j] + b2v[j]) * bf2f(h1v[mt][nt][j]);
            *(f32x4*)&m_s[e * 128 + (out0 ^ ((e & 7) << 2))] = mv;
        }
    }
    __syncthreads();

    // ---- phase E: segmented reduce by dst, flush via f32 atomics ----
    {
        const int ch = tid & 127;
        const int i0 = (tid >> 7) * 32;
        float sum = 0.f;
        int prev = dsts[i0];
        #pragma unroll 4
        for (int i = i0; i < i0 + 32; ++i) {
            int d = dsts[i];
            float v = m_s[i * 128 + (ch ^ ((i & 7) << 2))];
            if (d != prev) {
                atomicAdd(&agg[(size_t)prev * 128 + ch], sum);
                sum = 0.f; prev = d;
            }
            sum += v;
        }
        atomicAdd(&agg[(size_t)prev * 128 + ch], sum);
    }
}

extern "C" void kernel_launch(void* const* d_in, const int* in_sizes, int n_in,
                              void* d_out, int out_size, void* d_ws, size_t ws_size,
                              hipStream_t stream) {
    const float* h       = (const float*)d_in[0];
    const int*   ei      = (const int*)  d_in[1];
    const float* ew      = (const float*)d_in[2];
    const float* ea      = (const float*)d_in[3];
    const float* mlp_w0  = (const float*)d_in[4];
    const float* mlp_b0  = (const float*)d_in[5];
    const float* mlp_w2  = (const float*)d_in[6];
    const float* mlp_b2  = (const float*)d_in[7];
    const float* lin1_w  = (const float*)d_in[8];
    const float* lin2_w  = (const float*)d_in[9];
    const float* lin2_b  = (const float*)d_in[10];
    const float* lin_w   = (const float*)d_in[11];
    const float* lin_b   = (const float*)d_in[12];
    float* out = (float*)d_out;
    float* ws  = (float*)d_ws;

    const int N = in_sizes[0] / HID;            // 50000
    const int E = in_sizes[2];                  // 600000
    const int PADE = (E + 255) & ~255;          // 600064
    const int NODE_PAD = (N + 256) & ~255;      // 50176
    const int NSB = (N + 1023) / 1024;          // 49 scan blocks

    // ---- workspace layout (f32 slots) ----
    float* h1    = ws;                                   // N*128
    float* agg   = h1 + (size_t)N * 128;                 // N*128
    ushort_t* h1b = (ushort_t*)(agg + (size_t)N * 128);  // N*128 us
    ushort_t* l1b = (ushort_t*)((float*)h1b + (size_t)N * 64);
    ushort_t* l2b = l1b + 16384;
    ushort_t* lfb = l2b + 16384;
    ushort_t* w0b = lfb + 16384;                         // 8192 us
    ushort_t* w2b = w0b + 8192;                          // 16384 us
    int* counts  = (int*)(w2b + 16384);                  // NODE_PAD
    int* off     = counts + NODE_PAD;                    // NODE_PAD
    int* bsum    = off + NODE_PAD;                       // 64
    int* slot    = bsum + 64;                            // E
    int* eperm   = slot + E;                             // PADE
    ushort_t* eab = (ushort_t*)(eperm + PADE);           // PADE*64 us

    const int* srcI = ei;
    const int* dstI = ei + E;

    hipMemsetAsync(counts, 0, (size_t)NODE_PAD * 4, stream);
    hipMemsetAsync(agg, 0, (size_t)N * 128 * 4, stream);
    hipMemsetAsync(eab + (size_t)E * 64, 0, (size_t)(PADE - E) * 128, stream);

    prep_weights<<<288, 256, 0, stream>>>(lin1_w, lin2_w, lin_w, mlp_w0, mlp_w2,
                                          l1b, l2b, lfb, w0b, w2b);

    count_slots<<<(E + 255) / 256, 256, 0, stream>>>(dstI, counts, slot, E);
    scan1<<<NSB, 1024, 0, stream>>>(counts, off, bsum, N);
    scan2<<<1, 64, 0, stream>>>(bsum, NSB);
    scan3<<<NSB, 1024, 0, stream>>>(off, bsum, N);
    permute_ea2<<<(E * 8 + 255) / 256, 256, 0, stream>>>(dstI, slot, off, ea,
                                                         eab, eperm, E);

    int ngrid = (N + 127) / 128;
    // h1 = h @ lin1^T (+ bf16 copy for the gather)
    gemm_mfma<false, false, false, true><<<ngrid, 1024, 0, stream>>>(
        h, nullptr, l1b, nullptr, h1, h1b, N);

    // fused edge MLP + message + aggregation
    edge_fused<<<PADE / 256, 1024, 0, stream>>>(eab, eperm, srcI, dstI, ew,
                                                w0b, w2b, mlp_b0, mlp_b2,
                                                h1b, agg, E);

    // h2 = (h1 + agg) @ lin2^T + b2   (in-place into h1; block-local rows)
    gemm_mfma<true, false, true, false><<<ngrid, 1024, 0, stream>>>(
        h1, agg, l2b, lin2_b, h1, nullptr, N);
    // out = ssp(h2) @ lin^T + lin_b
    gemm_mfma<false, true, true, false><<<ngrid, 1024, 0, stream>>>(
        h1, nullptr, lfb, lin_b, out, nullptr, N);
}

// Round 6
// 270.197 us; speedup vs baseline: 5.1853x; 1.0589x over previous
//
#include <hip/hip_runtime.h>
#include <math.h>

#define HID 128
#define NF  128
#define NG  50

typedef unsigned short ushort_t;
typedef unsigned short us8 __attribute__((ext_vector_type(8)));
typedef unsigned short us4 __attribute__((ext_vector_type(4)));
typedef __bf16 bf16x8 __attribute__((ext_vector_type(8)));
typedef float f32x4 __attribute__((ext_vector_type(4)));

__device__ inline float ssp_fast(float x) {
    // softplus(x) - ln2 = max(x,0) + ln2*(log2(1+exp2(-|x|*log2e)) - 1)
    float t = __builtin_amdgcn_exp2f(fabsf(x) * -1.4426950408889634f);
    float l = __builtin_amdgcn_logf(1.0f + t);      // log2
    return fmaxf(x, 0.0f) + 0.6931471805599453f * (l - 1.0f);
}

__device__ inline ushort_t f2bf(float f) {
    return __builtin_bit_cast(ushort_t, (__bf16)f);
}
__device__ inline float bf2f(ushort_t h) {
    unsigned u = ((unsigned)h) << 16;
    return __builtin_bit_cast(float, u);
}

// async global->LDS, 16B per lane; LDS dest wave-uniform, global src per-lane
__device__ inline void gload16(const void* g, void* l) {
    __builtin_amdgcn_global_load_lds(
        (const __attribute__((address_space(1))) void*)g,
        (__attribute__((address_space(3))) void*)l, 16, 0, 0);
}

// ---------------- weight prep -----------------------------------------------
// l1b/l2b/lfb: bf16 swizzled (k ^ ((o&7)<<3)) for LDS-staged node GEMMs.
// w0g/w2g: bf16 PLAIN [o][k] (k padded to 64 for w0) for direct global frags.
__global__ void prep_weights(const float* __restrict__ lin1_w,
                             const float* __restrict__ lin2_w,
                             const float* __restrict__ lin_w,
                             const float* __restrict__ mlp_w0,
                             const float* __restrict__ mlp_w2,
                             ushort_t* __restrict__ l1b,
                             ushort_t* __restrict__ l2b,
                             ushort_t* __restrict__ lfb,
                             ushort_t* __restrict__ w0g,
                             ushort_t* __restrict__ w2g) {
    int idx = blockIdx.x * 256 + threadIdx.x;
    if (idx < 49152) {
        int m = idx >> 14, i = idx & 16383;
        int o = i >> 7, k = i & 127;
        const float* s = (m == 0) ? lin1_w : (m == 1) ? lin2_w : lin_w;
        ushort_t*    d = (m == 0) ? l1b    : (m == 1) ? l2b    : lfb;
        d[o * 128 + (k ^ ((o & 7) << 3))] = f2bf(s[i]);
    } else if (idx < 49152 + 8192) {
        int i = idx - 49152;            // o*64 + k
        int o = i >> 6, k = i & 63;
        float v = (k < 50) ? mlp_w0[o * 50 + k] : 0.f;
        w0g[i] = f2bf(v);
    } else if (idx < 49152 + 8192 + 16384) {
        int i = idx - 57344;            // o*128 + k
        w2g[i] = f2bf(mlp_w2[i]);
    }
}

// ---------------- CSR build -------------------------------------------------
__global__ void count_slots(const int* __restrict__ dst, int* counts,
                            int* __restrict__ slot, int E) {
    int e = blockIdx.x * 256 + threadIdx.x;
    if (e < E) slot[e] = atomicAdd(&counts[dst[e]], 1);
}
__global__ __launch_bounds__(1024) void scan1(const int* __restrict__ counts,
                                              int* __restrict__ off,
                                              int* __restrict__ bsum, int n) {
    __shared__ int s[1024];
    int t = threadIdx.x, g = blockIdx.x * 1024 + t;
    int c = (g < n) ? counts[g] : 0;
    s[t] = c;
    __syncthreads();
    for (int d = 1; d < 1024; d <<= 1) {
        int v = (t >= d) ? s[t - d] : 0;
        __syncthreads();
        s[t] += v;
        __syncthreads();
    }
    if (g < n) off[g] = s[t] - c;
    if (t == 1023) bsum[blockIdx.x] = s[1023];
}
__global__ void scan2(int* bsum, int nb) {
    __shared__ int s[64];
    int t = threadIdx.x;
    int v = (t < nb) ? bsum[t] : 0;
    s[t] = v;
    __syncthreads();
    for (int d = 1; d < 64; d <<= 1) {
        int u = (t >= d) ? s[t - d] : 0;
        __syncthreads();
        s[t] += u;
        __syncthreads();
    }
    if (t < nb) bsum[t] = s[t] - v;
}
__global__ __launch_bounds__(1024) void scan3(int* __restrict__ off,
                                              const int* __restrict__ bsum, int n) {
    int g = blockIdx.x * 1024 + threadIdx.x;
    if (g < n) off[g] += bsum[blockIdx.x];
}

// ---------------- permute: e-ordered read, p-scattered write ----------------
// 8 threads/edge; writes swizzled eab row + packed sidecar {src,dst,cw,0}.
__global__ __launch_bounds__(256) void permute_ea2(
    const int* __restrict__ srcI, const int* __restrict__ dstI,
    const int* __restrict__ slot, const int* __restrict__ off,
    const float* __restrict__ ea, const float* __restrict__ ew,
    ushort_t* __restrict__ eab, int4* __restrict__ sidecar, int E)
{
    int t = blockIdx.x * 256 + threadIdx.x;
    int e = t >> 3, q = t & 7;
    if (e >= E) return;
    int d = dstI[e];
    int p = off[d] + slot[e];
    const float* row = ea + (size_t)e * 50;
    us8 v = {0, 0, 0, 0, 0, 0, 0, 0};
    #pragma unroll
    for (int j = 0; j < 4; ++j) {
        int col = q * 8 + j * 2;
        if (col < 50) {
            float2 f = *(const float2*)(row + col);
            v[2 * j]     = f2bf(f.x);
            v[2 * j + 1] = f2bf(f.y);
        }
    }
    *(us8*)&eab[(size_t)p * 64 + ((q * 8) ^ ((p & 7) << 3))] = v;
    if (q == 0) {
        float cw = 0.5f * (__builtin_amdgcn_cosf(ew[e] * 0.05f) + 1.0f);
        sidecar[p] = make_int4(srcI[e], d, __float_as_int(cw), 0);
    }
}

// ---------------- node GEMM via bf16 MFMA (h1 producer) ---------------------
template<bool ADD2, bool PREACT, bool BIAS, bool H1B>
__global__ __launch_bounds__(1024, 4) void gemm_mfma(
    const float* __restrict__ A, const float* __restrict__ A2,
    const ushort_t* __restrict__ Wb, const float* __restrict__ bias,
    float* __restrict__ outF, ushort_t* __restrict__ outB, int n_rows)
{
    __shared__ ushort_t a_s[128 * 128];
    __shared__ ushort_t w_s[128 * 128];
    const int tid = threadIdx.x;
    const int n0 = blockIdx.x * 128;
    const int lane = tid & 63, wid = tid >> 6;

    #pragma unroll
    for (int i = 0; i < 2; ++i) {
        int cid = wid * 2 + i;
        gload16(Wb + cid * 512 + lane * 8, w_s + cid * 512);
    }
    {
        int r = tid >> 3, q = tid & 7;
        int n = n0 + r;
        float vals[16];
        if (n < n_rows) {
            #pragma unroll
            for (int j = 0; j < 4; ++j) {
                f32x4 v = ((const f32x4*)A)[(size_t)n * 32 + q * 4 + j];
                if (ADD2) v += ((const f32x4*)A2)[(size_t)n * 32 + q * 4 + j];
                #pragma unroll
                for (int x = 0; x < 4; ++x)
                    vals[j * 4 + x] = PREACT ? ssp_fast(v[x]) : v[x];
            }
        } else {
            #pragma unroll
            for (int x = 0; x < 16; ++x) vals[x] = 0.f;
        }
        int sw = (r & 7) << 3;
        #pragma unroll
        for (int hh = 0; hh < 2; ++hh) {
            us8 pk;
            #pragma unroll
            for (int x = 0; x < 8; ++x) pk[x] = f2bf(vals[hh * 8 + x]);
            *(us8*)&a_s[r * 128 + ((q * 16 + hh * 8) ^ sw)] = pk;
        }
    }
    __syncthreads();

    const int og = (wid >> 2) * 32;
    const int rg = (wid & 3) * 32;
    const int lm = lane & 15, lh = lane >> 4;

    f32x4 acc[2][2];
    #pragma unroll
    for (int mt = 0; mt < 2; ++mt)
        #pragma unroll
        for (int nt = 0; nt < 2; ++nt) acc[mt][nt] = (f32x4){0.f, 0.f, 0.f, 0.f};

    #pragma unroll
    for (int ks = 0; ks < 4; ++ks) {
        int k8 = ks * 32 + lh * 8;
        bf16x8 af[2], wf[2];
        #pragma unroll
        for (int mt = 0; mt < 2; ++mt) {
            int m = rg + mt * 16 + lm;
            af[mt] = __builtin_bit_cast(bf16x8,
                *(const us8*)&a_s[m * 128 + (k8 ^ ((m & 7) << 3))]);
        }
        #pragma unroll
        for (int nt = 0; nt < 2; ++nt) {
            int n = og + nt * 16 + lm;
            wf[nt] = __builtin_bit_cast(bf16x8,
                *(const us8*)&w_s[n * 128 + (k8 ^ ((n & 7) << 3))]);
        }
        #pragma unroll
        for (int mt = 0; mt < 2; ++mt)
            #pragma unroll
            for (int nt = 0; nt < 2; ++nt)
                acc[mt][nt] = __builtin_amdgcn_mfma_f32_16x16x32_bf16(
                    af[mt], wf[nt], acc[mt][nt], 0, 0, 0);
    }

    #pragma unroll
    for (int nt = 0; nt < 2; ++nt) {
        int outc = og + nt * 16 + lm;
        float bv = BIAS ? bias[outc] : 0.f;
        #pragma unroll
        for (int mt = 0; mt < 2; ++mt) {
            int rbase = rg + mt * 16 + lh * 4;
            #pragma unroll
            for (int j = 0; j < 4; ++j) {
                int n = n0 + rbase + j;
                if (n < n_rows) {
                    float v = acc[mt][nt][j] + bv;
                    outF[(size_t)n * 128 + outc] = v;
                    if (H1B) outB[(size_t)n * 128 + outc] = f2bf(v);
                }
            }
        }
    }
}

// ---------------- fused node GEMM2+3 ----------------------------------------
// h2 = (h1+agg)@l2^T + b2 ; out = ssp(h2)@lf^T + lb. One LDS round-trip.
__global__ __launch_bounds__(1024, 4) void gemm23_fused(
    const float* __restrict__ h1, const float* __restrict__ agg,
    const ushort_t* __restrict__ l2b, const float* __restrict__ b2,
    const ushort_t* __restrict__ lfb, const float* __restrict__ lb,
    float* __restrict__ outF, int n_rows)
{
    __shared__ ushort_t a_s[128 * 128];
    __shared__ ushort_t w_s[128 * 128];
    const int tid = threadIdx.x;
    const int n0 = blockIdx.x * 128;
    const int lane = tid & 63, wid = tid >> 6;

    #pragma unroll
    for (int i = 0; i < 2; ++i) {
        int cid = wid * 2 + i;
        gload16(l2b + cid * 512 + lane * 8, w_s + cid * 512);
    }
    {
        int r = tid >> 3, q = tid & 7;
        int n = n0 + r;
        float vals[16];
        if (n < n_rows) {
            #pragma unroll
            for (int j = 0; j < 4; ++j) {
                f32x4 v = ((const f32x4*)h1)[(size_t)n * 32 + q * 4 + j];
                v += ((const f32x4*)agg)[(size_t)n * 32 + q * 4 + j];
                #pragma unroll
                for (int x = 0; x < 4; ++x) vals[j * 4 + x] = v[x];
            }
        } else {
            #pragma unroll
            for (int x = 0; x < 16; ++x) vals[x] = 0.f;
        }
        int sw = (r & 7) << 3;
        #pragma unroll
        for (int hh = 0; hh < 2; ++hh) {
            us8 pk;
            #pragma unroll
            for (int x = 0; x < 8; ++x) pk[x] = f2bf(vals[hh * 8 + x]);
            *(us8*)&a_s[r * 128 + ((q * 16 + hh * 8) ^ sw)] = pk;
        }
    }
    __syncthreads();

    const int og = (wid >> 2) * 32;
    const int rg = (wid & 3) * 32;
    const int lm = lane & 15, lh = lane >> 4;

    f32x4 acc[2][2];
    #pragma unroll
    for (int mt = 0; mt < 2; ++mt)
        #pragma unroll
        for (int nt = 0; nt < 2; ++nt) acc[mt][nt] = (f32x4){0.f, 0.f, 0.f, 0.f};
    #pragma unroll
    for (int ks = 0; ks < 4; ++ks) {
        int k8 = ks * 32 + lh * 8;
        bf16x8 af[2], wf[2];
        #pragma unroll
        for (int mt = 0; mt < 2; ++mt) {
            int m = rg + mt * 16 + lm;
            af[mt] = __builtin_bit_cast(bf16x8,
                *(const us8*)&a_s[m * 128 + (k8 ^ ((m & 7) << 3))]);
        }
        #pragma unroll
        for (int nt = 0; nt < 2; ++nt) {
            int n = og + nt * 16 + lm;
            wf[nt] = __builtin_bit_cast(bf16x8,
                *(const us8*)&w_s[n * 128 + (k8 ^ ((n & 7) << 3))]);
        }
        #pragma unroll
        for (int mt = 0; mt < 2; ++mt)
            #pragma unroll
            for (int nt = 0; nt < 2; ++nt)
                acc[mt][nt] = __builtin_amdgcn_mfma_f32_16x16x32_bf16(
                    af[mt], wf[nt], acc[mt][nt], 0, 0, 0);
    }
    __syncthreads();        // all a_s / w_s reads complete

    // restage w_s <- lfb; write u = ssp(h2) into a_s (swizzled [row][out])
    #pragma unroll
    for (int i = 0; i < 2; ++i) {
        int cid = wid * 2 + i;
        gload16(lfb + cid * 512 + lane * 8, w_s + cid * 512);
    }
    #pragma unroll
    for (int nt = 0; nt < 2; ++nt) {
        int outc = og + nt * 16 + lm;
        float bv = b2[outc];
        #pragma unroll
        for (int mt = 0; mt < 2; ++mt) {
            int rbase = rg + mt * 16 + lh * 4;
            #pragma unroll
            for (int j = 0; j < 4; ++j) {
                int r = rbase + j;
                a_s[r * 128 + (outc ^ ((r & 7) << 3))] =
                    f2bf(ssp_fast(acc[mt][nt][j] + bv));
            }
        }
    }
    __syncthreads();

    f32x4 acc2[2][2];
    #pragma unroll
    for (int mt = 0; mt < 2; ++mt)
        #pragma unroll
        for (int nt = 0; nt < 2; ++nt) acc2[mt][nt] = (f32x4){0.f, 0.f, 0.f, 0.f};
    #pragma unroll
    for (int ks = 0; ks < 4; ++ks) {
        int k8 = ks * 32 + lh * 8;
        bf16x8 af[2], wf[2];
        #pragma unroll
        for (int mt = 0; mt < 2; ++mt) {
            int m = rg + mt * 16 + lm;
            af[mt] = __builtin_bit_cast(bf16x8,
                *(const us8*)&a_s[m * 128 + (k8 ^ ((m & 7) << 3))]);
        }
        #pragma unroll
        for (int nt = 0; nt < 2; ++nt) {
            int n = og + nt * 16 + lm;
            wf[nt] = __builtin_bit_cast(bf16x8,
                *(const us8*)&w_s[n * 128 + (k8 ^ ((n & 7) << 3))]);
        }
        #pragma unroll
        for (int mt = 0; mt < 2; ++mt)
            #pragma unroll
            for (int nt = 0; nt < 2; ++nt)
                acc2[mt][nt] = __builtin_amdgcn_mfma_f32_16x16x32_bf16(
                    af[mt], wf[nt], acc2[mt][nt], 0, 0, 0);
    }

    #pragma unroll
    for (int nt = 0; nt < 2; ++nt) {
        int outc = og + nt * 16 + lm;
        float bv = lb[outc];
        #pragma unroll
        for (int mt = 0; mt < 2; ++mt) {
            int rbase = rg + mt * 16 + lh * 4;
            #pragma unroll
            for (int j = 0; j < 4; ++j) {
                int n = n0 + rbase + j;
                if (n < n_rows)
                    outF[(size_t)n * 128 + outc] = acc2[mt][nt][j] + bv;
            }
        }
    }
}

// ---------------- fused edge MLP + message + segmented aggregation ---------
// 512 thr = 8 waves (4 out-groups x 2 edge-groups); 128 CSR positions/block.
// Weights consumed directly from global (L2-resident) as register fragments.
__global__ __launch_bounds__(512, 4) void edge_fused(
    const ushort_t* __restrict__ eab, const int4* __restrict__ sidecar,
    const ushort_t* __restrict__ w0g, const ushort_t* __restrict__ w2g,
    const float* __restrict__ b0g, const float* __restrict__ b2g,
    const ushort_t* __restrict__ h1b, float* __restrict__ agg)
{
    __shared__ __align__(16) char blob[67072];
    ushort_t* ea_s = (ushort_t*)blob;             // 16 KB
    ushort_t* u_s  = (ushort_t*)(blob + 16384);   // 32 KB
    float*    m_s  = (float*)blob;                // 64 KB overlay (phase D/E)
    float* cws  = (float*)(blob + 65536);
    int*   srcs = (int*)(blob + 66048);
    int*   dsts = (int*)(blob + 66560);

    const int tid = threadIdx.x;
    const int p0 = blockIdx.x * 128;
    const int lane = tid & 63, wid = tid >> 6;
    const int out0w = (wid >> 1) * 32;   // 4 out-groups of 32
    const int e0w   = (wid & 1) * 64;    // 2 edge-groups of 64
    const int lm = lane & 15, lh = lane >> 4;

    // ---- stage ea (16 x 1KB chunks) + sidecar ----
    #pragma unroll
    for (int i = 0; i < 2; ++i) {
        int cid = wid * 2 + i;
        gload16(eab + (size_t)p0 * 64 + cid * 512 + lane * 8, ea_s + cid * 512);
    }
    if (tid < 128) {
        int4 sc = sidecar[p0 + tid];
        srcs[tid] = sc.x; dsts[tid] = sc.y; cws[tid] = __int_as_float(sc.z);
    }

    // weight fragments from global (L2-hit; hidden under staging barrier)
    bf16x8 w0f[2][2], w2f[4][2];
    #pragma unroll
    for (int ks = 0; ks < 2; ++ks)
        #pragma unroll
        for (int mt = 0; mt < 2; ++mt) {
            int n = out0w + mt * 16 + lm;
            w0f[ks][mt] = __builtin_bit_cast(bf16x8,
                *(const us8*)&w0g[n * 64 + ks * 32 + lh * 8]);
        }
    #pragma unroll
    for (int ks = 0; ks < 4; ++ks)
        #pragma unroll
        for (int mt = 0; mt < 2; ++mt) {
            int n = out0w + mt * 16 + lm;
            w2f[ks][mt] = __builtin_bit_cast(bf16x8,
                *(const us8*)&w2g[n * 128 + ks * 32 + lh * 8]);
        }
    __syncthreads();

    int sv[4];
    #pragma unroll
    for (int nt = 0; nt < 4; ++nt) sv[nt] = srcs[e0w + nt * 16 + lm];

    // ---- GEMM1: t^T = w0 * ea^T  (K = 64 padded) ----
    f32x4 acc1[2][4];
    #pragma unroll
    for (int mt = 0; mt < 2; ++mt)
        #pragma unroll
        for (int nt = 0; nt < 4; ++nt) acc1[mt][nt] = (f32x4){0.f, 0.f, 0.f, 0.f};
    #pragma unroll
    for (int ks = 0; ks < 2; ++ks) {
        int k8 = ks * 32 + lh * 8;
        #pragma unroll
        for (int nt = 0; nt < 4; ++nt) {
            int e = e0w + nt * 16 + lm;
            bf16x8 be = __builtin_bit_cast(bf16x8,
                *(const us8*)&ea_s[e * 64 + (k8 ^ ((e & 7) << 3))]);
            #pragma unroll
            for (int mt = 0; mt < 2; ++mt)
                acc1[mt][nt] = __builtin_amdgcn_mfma_f32_16x16x32_bf16(
                    w0f[ks][mt], be, acc1[mt][nt], 0, 0, 0);
        }
    }

    // h1 gather issued here -> hidden under epilogue1 + GEMM2
    us4 h1v[2][4];
    #pragma unroll
    for (int mt = 0; mt < 2; ++mt) {
        int out0 = out0w + mt * 16 + lh * 4;
        #pragma unroll
        for (int nt = 0; nt < 4; ++nt)
            h1v[mt][nt] = *(const us4*)&h1b[(size_t)sv[nt] * 128 + out0];
    }

    // epilogue1: u = ssp(t + b0) -> packed 4xbf16 ds_write_b64
    #pragma unroll
    for (int mt = 0; mt < 2; ++mt) {
        int out0 = out0w + mt * 16 + lh * 4;
        f32x4 b0v = *(const f32x4*)&b0g[out0];
        #pragma unroll
        for (int nt = 0; nt < 4; ++nt) {
            int e = e0w + nt * 16 + lm;
            us4 pk;
            #pragma unroll
            for (int j = 0; j < 4; ++j)
                pk[j] = f2bf(ssp_fast(acc1[mt][nt][j] + b0v[j]));
            *(us4*)&u_s[e * 128 + (out0 ^ ((e & 7) << 3))] = pk;
        }
    }
    __syncthreads();

    // ---- GEMM2: W^T = w2 * u^T  (K = 128) ----
    f32x4 acc2[2][4];
    #pragma unroll
    for (int mt = 0; mt < 2; ++mt)
        #pragma unroll
        for (int nt = 0; nt < 4; ++nt) acc2[mt][nt] = (f32x4){0.f, 0.f, 0.f, 0.f};
    #pragma unroll
    for (int ks = 0; ks < 4; ++ks) {
        int k8 = ks * 32 + lh * 8;
        #pragma unroll
        for (int nt = 0; nt < 4; ++nt) {
            int e = e0w + nt * 16 + lm;
            bf16x8 be = __builtin_bit_cast(bf16x8,
                *(const us8*)&u_s[e * 128 + (k8 ^ ((e & 7) << 3))]);
            #pragma unroll
            for (int mt = 0; mt < 2; ++mt)
                acc2[mt][nt] = __builtin_amdgcn_mfma_f32_16x16x32_bf16(
                    w2f[ks][mt], be, acc2[mt][nt], 0, 0, 0);
        }
    }
    __syncthreads();    // ea_s/u_s reads done; m_s overlay now safe

    // ---- phase D: m = c * (W + b2) * h1[src]  -> f32 LDS (swizzled) ----
    #pragma unroll
    for (int mt = 0; mt < 2; ++mt) {
        int out0 = out0w + mt * 16 + lh * 4;
        f32x4 b2v = *(const f32x4*)&b2g[out0];
        #pragma unroll
        for (int nt = 0; nt < 4; ++nt) {
            int e = e0w + nt * 16 + lm;
            float cvv = cws[e];
            f32x4 mv;
            #pragma unroll
            for (int j = 0; j < 4; ++j)
                mv[j] = cvv * (acc2[mt][nt][j] + b2v[j]) * bf2f(h1v[mt][nt][j]);
            *(f32x4*)&m_s[e * 128 + (out0 ^ ((e & 7) << 2))] = mv;
        }
    }
    __syncthreads();

    // ---- phase E: segmented reduce by dst, flush via f32 atomics ----
    {
        const int ch = tid & 127;
        const int i0 = (tid >> 7) * 32;      // 4 segments x 32 edges
        float sum = 0.f;
        int prev = dsts[i0];
        #pragma unroll 4
        for (int i = i0; i < i0 + 32; ++i) {
            int d = dsts[i];
            float v = m_s[i * 128 + (ch ^ ((i & 7) << 2))];
            if (d != prev) {
                atomicAdd(&agg[(size_t)prev * 128 + ch], sum);
                sum = 0.f; prev = d;
            }
            sum += v;
        }
        atomicAdd(&agg[(size_t)prev * 128 + ch], sum);
    }
}

extern "C" void kernel_launch(void* const* d_in, const int* in_sizes, int n_in,
                              void* d_out, int out_size, void* d_ws, size_t ws_size,
                              hipStream_t stream) {
    const float* h       = (const float*)d_in[0];
    const int*   ei      = (const int*)  d_in[1];
    const float* ew      = (const float*)d_in[2];
    const float* ea      = (const float*)d_in[3];
    const float* mlp_w0  = (const float*)d_in[4];
    const float* mlp_b0  = (const float*)d_in[5];
    const float* mlp_w2  = (const float*)d_in[6];
    const float* mlp_b2  = (const float*)d_in[7];
    const float* lin1_w  = (const float*)d_in[8];
    const float* lin2_w  = (const float*)d_in[9];
    const float* lin2_b  = (const float*)d_in[10];
    const float* lin_w   = (const float*)d_in[11];
    const float* lin_b   = (const float*)d_in[12];
    float* out = (float*)d_out;
    float* ws  = (float*)d_ws;

    const int N = in_sizes[0] / HID;            // 50000
    const int E = in_sizes[2];                  // 600000
    const int PADE = (E + 127) & ~127;          // 600064
    const int NODE_PAD = (N + 256) & ~255;      // 50176
    const int NSB = (N + 1023) / 1024;          // 49 scan blocks

    // ---- workspace layout (f32 slots) ----
    float* h1    = ws;                                   // N*128
    float* agg   = h1 + (size_t)N * 128;                 // N*128
    ushort_t* h1b = (ushort_t*)(agg + (size_t)N * 128);  // N*128 us
    ushort_t* l1b = (ushort_t*)((float*)h1b + (size_t)N * 64);
    ushort_t* l2b = l1b + 16384;
    ushort_t* lfb = l2b + 16384;
    ushort_t* w0g = lfb + 16384;                         // 8192 us
    ushort_t* w2g = w0g + 8192;                          // 16384 us
    int* counts  = (int*)(w2g + 16384);                  // NODE_PAD
    int* off     = counts + NODE_PAD;                    // NODE_PAD
    int* bsum    = off + NODE_PAD;                       // 64
    int* slot    = bsum + 64;                            // E
    int4* sidecar = (int4*)(slot + E);                   // PADE int4
    ushort_t* eab = (ushort_t*)((int*)sidecar + (size_t)PADE * 4);  // PADE*64 us

    const int* srcI = ei;
    const int* dstI = ei + E;

    hipMemsetAsync(counts, 0, (size_t)NODE_PAD * 4, stream);
    hipMemsetAsync(agg, 0, (size_t)N * 128 * 4, stream);
    hipMemsetAsync(sidecar + E, 0, (size_t)(PADE - E) * 16, stream);
    hipMemsetAsync(eab + (size_t)E * 64, 0, (size_t)(PADE - E) * 128, stream);

    prep_weights<<<288, 256, 0, stream>>>(lin1_w, lin2_w, lin_w, mlp_w0, mlp_w2,
                                          l1b, l2b, lfb, w0g, w2g);

    count_slots<<<(E + 255) / 256, 256, 0, stream>>>(dstI, counts, slot, E);
    scan1<<<NSB, 1024, 0, stream>>>(counts, off, bsum, N);
    scan2<<<1, 64, 0, stream>>>(bsum, NSB);
    scan3<<<NSB, 1024, 0, stream>>>(off, bsum, N);
    permute_ea2<<<((size_t)E * 8 + 255) / 256, 256, 0, stream>>>(
        srcI, dstI, slot, off, ea, ew, eab, sidecar, E);

    int ngrid = (N + 127) / 128;
    // h1 = h @ lin1^T (+ bf16 copy for the gather)
    gemm_mfma<false, false, false, true><<<ngrid, 1024, 0, stream>>>(
        h, nullptr, l1b, nullptr, h1, h1b, N);

    // fused edge MLP + message + aggregation
    edge_fused<<<PADE / 128, 512, 0, stream>>>(eab, sidecar, w0g, w2g,
                                               mlp_b0, mlp_b2, h1b, agg);

    // out = ssp((h1+agg)@lin2^T + b2) @ lin^T + lin_b
    gemm23_fused<<<ngrid, 1024, 0, stream>>>(h1, agg, l2b, lin2_b,
                                             lfb, lin_b, out, N);
}